// Round 2
// baseline (1603.718 us; speedup 1.0000x reference)
//
#include <hip/hip_runtime.h>
#include <cmath>

#define D 64
#define SCAN_CHUNK 1024   // elements per scan block
#define PA_EDGES 4096     // edges per partition block
#define BSHIFT 7          // bucket = 128 nodes
#define BNODES 128
#define MAXBUCK 1024      // supports N <= 131072

// ---------------------------------------------------------------------------
// CSR-degree build: histogram of dst + exclusive scan -> rowStart.
// ---------------------------------------------------------------------------
__global__ void hist_kernel(const int* __restrict__ dst, int* __restrict__ cnt, int E) {
    int t = blockIdx.x * blockDim.x + threadIdx.x;
    if (t < E) atomicAdd(&cnt[dst[t]], 1);
}

__global__ void block_sums_kernel(const int* __restrict__ cnt, int* __restrict__ bsum, int n) {
    __shared__ int red[256];
    int base = blockIdx.x * SCAN_CHUNK;
    int s = 0;
    for (int i = threadIdx.x; i < SCAN_CHUNK; i += 256) {
        int idx = base + i;
        s += (idx < n) ? cnt[idx] : 0;
    }
    red[threadIdx.x] = s;
    __syncthreads();
    for (int off = 128; off > 0; off >>= 1) {
        if (threadIdx.x < off) red[threadIdx.x] += red[threadIdx.x + off];
        __syncthreads();
    }
    if (threadIdx.x == 0) bsum[blockIdx.x] = red[0];
}

__global__ void scan_bsums_kernel(int* __restrict__ bsum, int nb) {
    __shared__ int s[256];
    int t = threadIdx.x;
    s[t] = (t < nb) ? bsum[t] : 0;
    __syncthreads();
    for (int off = 1; off < 256; off <<= 1) {
        int u = (t >= off) ? s[t - off] : 0;
        __syncthreads();
        s[t] += u;
        __syncthreads();
    }
    if (t < nb) bsum[t] = (t == 0) ? 0 : s[t - 1];   // exclusive
}

__global__ void scan_final_kernel(const int* __restrict__ cnt, const int* __restrict__ bsum,
                                  int* __restrict__ rowStart, int n, int E) {
    __shared__ int red[256];
    int t = threadIdx.x;
    int idx = blockIdx.x * SCAN_CHUNK + t * 4;
    int v0 = (idx + 0 < n) ? cnt[idx + 0] : 0;
    int v1 = (idx + 1 < n) ? cnt[idx + 1] : 0;
    int v2 = (idx + 2 < n) ? cnt[idx + 2] : 0;
    int v3 = (idx + 3 < n) ? cnt[idx + 3] : 0;
    red[t] = v0 + v1 + v2 + v3;
    __syncthreads();
    for (int off = 1; off < 256; off <<= 1) {
        int u = (t >= off) ? red[t - off] : 0;
        __syncthreads();
        red[t] += u;
        __syncthreads();
    }
    int excl = ((t == 0) ? 0 : red[t - 1]) + bsum[blockIdx.x];
    if (idx + 0 < n) rowStart[idx + 0] = excl;
    if (idx + 1 < n) rowStart[idx + 1] = excl + v0;
    if (idx + 2 < n) rowStart[idx + 2] = excl + v0 + v1;
    if (idx + 3 < n) rowStart[idx + 3] = excl + v0 + v1 + v2;
    if (blockIdx.x == 0 && t == 0) rowStart[n] = E;
}

__global__ __launch_bounds__(256)
void cursor_init_kernel(const int* __restrict__ rowStart, int* __restrict__ cursor,
                        int n, int nbuck) {
    int b = blockIdx.x * blockDim.x + threadIdx.x;
    if (b < nbuck) cursor[b] = rowStart[min(b << BSHIFT, n)];
}

// ---------------------------------------------------------------------------
// Bucket partition: (src, dst) -> packed 32-bit (src<<7 | dst&127), grouped
// by bucket (dst>>7) in `pairs`. LDS-staged so global writes are contiguous
// segments. Supersedes the csr fill entirely.
// ---------------------------------------------------------------------------
__global__ __launch_bounds__(256)
void partition_kernel(const int* __restrict__ src, const int* __restrict__ dst,
                      int* __restrict__ cursor, unsigned* __restrict__ pairs,
                      int E, int nbuck) {
    __shared__ int lhist[MAXBUCK];        // counts, then local fill cursors
    __shared__ int lbase[MAXBUCK + 1];    // local exclusive scan
    __shared__ int gbase[MAXBUCK];        // reserved global positions
    __shared__ int red[256];
    __shared__ unsigned stage[PA_EDGES];  // 16 KB

    const int t = threadIdx.x;
    const int e0 = blockIdx.x * PA_EDGES;
    const int ecnt = min(PA_EDGES, E - e0);

    for (int i = t; i < MAXBUCK; i += 256) lhist[i] = 0;
    __syncthreads();
    for (int i = t; i < ecnt; i += 256) atomicAdd(&lhist[dst[e0 + i] >> BSHIFT], 1);
    __syncthreads();

    // exclusive scan over 1024 entries: each thread owns 4 consecutive slots
    const int c0 = lhist[4 * t], c1 = lhist[4 * t + 1];
    const int c2 = lhist[4 * t + 2], c3 = lhist[4 * t + 3];
    red[t] = c0 + c1 + c2 + c3;
    __syncthreads();
    for (int off = 1; off < 256; off <<= 1) {
        int u = (t >= off) ? red[t - off] : 0;
        __syncthreads();
        red[t] += u;
        __syncthreads();
    }
    const int excl = (t == 0) ? 0 : red[t - 1];
    lbase[4 * t]     = excl;
    lbase[4 * t + 1] = excl + c0;
    lbase[4 * t + 2] = excl + c0 + c1;
    lbase[4 * t + 3] = excl + c0 + c1 + c2;
    if (t == 255) lbase[MAXBUCK] = red[255];
    // reserve global space per non-empty bucket
    for (int b = t; b < nbuck; b += 256) {
        const int c = lhist[b];
        gbase[b] = c ? atomicAdd(&cursor[b], c) : 0;
    }
    __syncthreads();
    for (int i = t; i < MAXBUCK; i += 256) lhist[i] = 0;   // reuse as fill cursors
    __syncthreads();
    // bucket-ordered scatter into LDS stage (packed)
    for (int i = t; i < ecnt; i += 256) {
        const int d = dst[e0 + i];
        const int b = d >> BSHIFT;
        const int p = lbase[b] + atomicAdd(&lhist[b], 1);
        stage[p] = ((unsigned)src[e0 + i] << BSHIFT) | (unsigned)(d & (BNODES - 1));
    }
    __syncthreads();
    // coalesced-segment write-out; bucket of slot i via upper_bound(lbase)-1
    for (int i = t; i < ecnt; i += 256) {
        int lo = 0, hi = MAXBUCK;
        while (hi - lo > 1) {
            const int mid = (lo + hi) >> 1;
            if (lbase[mid] <= i) lo = mid; else hi = mid;
        }
        pairs[gbase[lo] + (i - lbase[lo])] = stage[i];
    }
}

// ---------------------------------------------------------------------------
// Edge-parallel gather-mean: m[node] = mean(x[nbrs(node)]). One block per
// 128-node bucket, 32 KB LDS fp32 accumulator, 8 waves. Every edge is an
// independent {row gather -> ds_add_f32}, 8 in flight per wave: no csr->
// gather dependency chain, no per-node serial tail (the latency killers of
// the old per-node agg).
// ---------------------------------------------------------------------------
__global__ __launch_bounds__(512, 8)
void aggmean_kernel(const float* __restrict__ xin, const unsigned* __restrict__ pairs,
                    const int* __restrict__ rowStart, float* __restrict__ m, int n) {
    __shared__ float acc[BNODES * D];     // 32 KB
    __shared__ int lrow[BNODES + 1];
    const int t = threadIdx.x;
    const int lane = t & 63;
    const int wave = t >> 6;              // 0..7
    const int node0 = blockIdx.x << BSHIFT;
    const int bn = min(BNODES, n - node0);

    for (int i = t; i < BNODES * D / 4; i += 512)
        ((float4*)acc)[i] = make_float4(0.f, 0.f, 0.f, 0.f);
    if (t <= BNODES) lrow[t] = rowStart[min(node0 + t, n)];
    __syncthreads();

    const int ebase = lrow[0];
    const int ecnt = lrow[bn] - ebase;

    for (int c = wave * 64; c < ecnt; c += 8 * 64) {
        const int cnt = min(64, ecnt - c);
        const unsigned pk = (lane < cnt) ? pairs[ebase + c + lane] : 0u;
        int k = 0;
        for (; k + 8 <= cnt; k += 8) {
            const unsigned p0 = (unsigned)__builtin_amdgcn_readlane((int)pk, k + 0);
            const unsigned p1 = (unsigned)__builtin_amdgcn_readlane((int)pk, k + 1);
            const unsigned p2 = (unsigned)__builtin_amdgcn_readlane((int)pk, k + 2);
            const unsigned p3 = (unsigned)__builtin_amdgcn_readlane((int)pk, k + 3);
            const unsigned p4 = (unsigned)__builtin_amdgcn_readlane((int)pk, k + 4);
            const unsigned p5 = (unsigned)__builtin_amdgcn_readlane((int)pk, k + 5);
            const unsigned p6 = (unsigned)__builtin_amdgcn_readlane((int)pk, k + 6);
            const unsigned p7 = (unsigned)__builtin_amdgcn_readlane((int)pk, k + 7);
            const float v0 = xin[(size_t)(p0 >> BSHIFT) * D + lane];
            const float v1 = xin[(size_t)(p1 >> BSHIFT) * D + lane];
            const float v2 = xin[(size_t)(p2 >> BSHIFT) * D + lane];
            const float v3 = xin[(size_t)(p3 >> BSHIFT) * D + lane];
            const float v4 = xin[(size_t)(p4 >> BSHIFT) * D + lane];
            const float v5 = xin[(size_t)(p5 >> BSHIFT) * D + lane];
            const float v6 = xin[(size_t)(p6 >> BSHIFT) * D + lane];
            const float v7 = xin[(size_t)(p7 >> BSHIFT) * D + lane];
            atomicAdd(&acc[(p0 & (BNODES - 1)) * D + lane], v0);
            atomicAdd(&acc[(p1 & (BNODES - 1)) * D + lane], v1);
            atomicAdd(&acc[(p2 & (BNODES - 1)) * D + lane], v2);
            atomicAdd(&acc[(p3 & (BNODES - 1)) * D + lane], v3);
            atomicAdd(&acc[(p4 & (BNODES - 1)) * D + lane], v4);
            atomicAdd(&acc[(p5 & (BNODES - 1)) * D + lane], v5);
            atomicAdd(&acc[(p6 & (BNODES - 1)) * D + lane], v6);
            atomicAdd(&acc[(p7 & (BNODES - 1)) * D + lane], v7);
        }
        for (; k < cnt; ++k) {
            const unsigned p = (unsigned)__builtin_amdgcn_readlane((int)pk, k);
            atomicAdd(&acc[(p & (BNODES - 1)) * D + lane],
                      xin[(size_t)(p >> BSHIFT) * D + lane]);
        }
    }
    __syncthreads();

    for (int i = t; i < bn * D; i += 512) {
        const int node = i >> 6;
        const float deg = (float)(lrow[node + 1] - lrow[node]);
        m[(size_t)node0 * D + i] = acc[i] / fmaxf(deg, 1.0f);
    }
}

// ---------------------------------------------------------------------------
// Fused SAGE transform: h = ELU(m@Wa + ba + x@Wb). Both weight columns
// register-resident (128 VGPR); input rows broadcast via readlane.
// FINAL: out = h@Wlin + blin chained (third register column).
// ---------------------------------------------------------------------------
template <bool FINAL>
__global__ __launch_bounds__(256, 2)
void fused_mm_kernel(const float* __restrict__ m,
                     const float* __restrict__ xres,
                     const float* __restrict__ Wa,
                     const float* __restrict__ ba,
                     const float* __restrict__ Wb,
                     const float* __restrict__ Wlin,
                     const float* __restrict__ blin,
                     float* __restrict__ out,
                     int n) {
    const int lane = threadIdx.x & 63;
    const int wave = threadIdx.x >> 6;
    const int gw = blockIdx.x * 4 + wave;
    const int nw = gridDim.x * 4;

    float wa[D], wb[D], wl[FINAL ? D : 1];
#pragma unroll
    for (int k = 0; k < D; ++k) wa[k] = Wa[k * D + lane];   // column `lane`
#pragma unroll
    for (int k = 0; k < D; ++k) wb[k] = Wb[k * D + lane];
    if (FINAL) {
#pragma unroll
        for (int k = 0; k < D; ++k) wl[k] = Wlin[k * D + lane];
    }
    const float bva = ba[lane];
    const float bvl = FINAL ? blin[lane] : 0.0f;

    for (int node = gw; node < n; node += nw) {
        const unsigned mu = __float_as_uint(m[(size_t)node * D + lane]);
        const unsigned xu = __float_as_uint(xres[(size_t)node * D + lane]);
        float o0 = bva, o1 = 0.0f, o2 = 0.0f, o3 = 0.0f;
#pragma unroll
        for (int k = 0; k < D; k += 4) {
            const float sm0 = __uint_as_float(__builtin_amdgcn_readlane(mu, k + 0));
            const float sm1 = __uint_as_float(__builtin_amdgcn_readlane(mu, k + 1));
            const float sm2 = __uint_as_float(__builtin_amdgcn_readlane(mu, k + 2));
            const float sm3 = __uint_as_float(__builtin_amdgcn_readlane(mu, k + 3));
            const float sx0 = __uint_as_float(__builtin_amdgcn_readlane(xu, k + 0));
            const float sx1 = __uint_as_float(__builtin_amdgcn_readlane(xu, k + 1));
            const float sx2 = __uint_as_float(__builtin_amdgcn_readlane(xu, k + 2));
            const float sx3 = __uint_as_float(__builtin_amdgcn_readlane(xu, k + 3));
            o0 = fmaf(sm0, wa[k + 0], o0); o0 = fmaf(sx0, wb[k + 0], o0);
            o1 = fmaf(sm1, wa[k + 1], o1); o1 = fmaf(sx1, wb[k + 1], o1);
            o2 = fmaf(sm2, wa[k + 2], o2); o2 = fmaf(sx2, wb[k + 2], o2);
            o3 = fmaf(sm3, wa[k + 3], o3); o3 = fmaf(sx3, wb[k + 3], o3);
        }
        float h = (o0 + o1) + (o2 + o3);
        h = h > 0.0f ? h : expm1f(h);   // ELU(alpha=1)

        if (FINAL) {
            float o = bvl;
            const unsigned hu = __float_as_uint(h);
#pragma unroll
            for (int k = 0; k < D; ++k) {
                const float hk = __uint_as_float(__builtin_amdgcn_readlane(hu, k));
                o = fmaf(hk, wl[k], o);
            }
            out[(size_t)node * D + lane] = o;
        } else {
            out[(size_t)node * D + lane] = h;
        }
    }
}

extern "C" void kernel_launch(void* const* d_in, const int* in_sizes, int n_in,
                              void* d_out, int out_size, void* d_ws, size_t ws_size,
                              hipStream_t stream) {
    const float* x    = (const float*)d_in[0];
    const int*   ei   = (const int*)d_in[1];
    const float* W1l  = (const float*)d_in[2];
    const float* b1   = (const float*)d_in[3];
    const float* W1r  = (const float*)d_in[4];
    const float* W2l  = (const float*)d_in[5];
    const float* b2   = (const float*)d_in[6];
    const float* W2r  = (const float*)d_in[7];
    const float* Wlin = (const float*)d_in[8];
    const float* blin = (const float*)d_in[9];

    const int N_ = in_sizes[0] / D;      // 100000
    const int E_ = in_sizes[1] / 2;      // 1600000
    const int* src = ei;
    const int* dst = ei + E_;

    // workspace layout
    int* cnt      = (int*)d_ws;                     // N
    int* rowStart = cnt + N_;                       // N+1
    int* bsum     = rowStart + N_ + 1;              // 256
    int* cursor   = bsum + 256;                     // MAXBUCK
    unsigned* pairs = (unsigned*)(cursor + MAXBUCK);// E (packed src<<7|dloc)
    float* mbuf   = (float*)(pairs + E_);           // N*64 (aggregated mean)
    float* hbuf   = mbuf + (size_t)N_ * D;          // N*64 (h1)

    const int nb    = (N_ + SCAN_CHUNK - 1) / SCAN_CHUNK;   // 98
    const int nbuck = (N_ + BNODES - 1) >> BSHIFT;          // 782

    hipMemsetAsync(cnt, 0, (size_t)N_ * sizeof(int), stream);

    hist_kernel<<<(E_ + 255) / 256, 256, 0, stream>>>(dst, cnt, E_);
    block_sums_kernel<<<nb, 256, 0, stream>>>(cnt, bsum, N_);
    scan_bsums_kernel<<<1, 256, 0, stream>>>(bsum, nb);
    scan_final_kernel<<<nb, 256, 0, stream>>>(cnt, bsum, rowStart, N_, E_);
    cursor_init_kernel<<<(nbuck + 255) / 256, 256, 0, stream>>>(rowStart, cursor, N_, nbuck);
    partition_kernel<<<(E_ + PA_EDGES - 1) / PA_EDGES, 256, 0, stream>>>(
        src, dst, cursor, pairs, E_, nbuck);

    // Layer 1: m1 = mean(x[nbrs]) ; h1 = ELU(m1@W1l + b1 + x@W1r)
    aggmean_kernel<<<nbuck, 512, 0, stream>>>(x, pairs, rowStart, mbuf, N_);
    fused_mm_kernel<false><<<2048, 256, 0, stream>>>(mbuf, x, W1l, b1, W1r,
                                                     nullptr, nullptr, hbuf, N_);
    // Layer 2: m2 = mean(h1[nbrs]) ; out = ELU(m2@W2l + b2 + h1@W2r) @ Wlin + blin
    aggmean_kernel<<<nbuck, 512, 0, stream>>>(hbuf, pairs, rowStart, mbuf, N_);
    fused_mm_kernel<true><<<2048, 256, 0, stream>>>(mbuf, hbuf, W2l, b2, W2r,
                                                    Wlin, blin, (float*)d_out, N_);
}

// Round 3
// 400.514 us; speedup vs baseline: 4.0041x; 4.0041x over previous
//
#include <hip/hip_runtime.h>
#include <cmath>

#define D 64
#define SCAN_CHUNK 1024   // elements per scan block
#define PA_EDGES 4096     // edges per partition block
#define BSHIFT 7          // bucket = 128 nodes
#define BNODES 128
#define MAXBUCK 1024      // supports N <= 131072
#define PB_CAP 4096       // LDS csr staging per bucket (avg 2048, ~45 sigma)

// ---------------------------------------------------------------------------
// CSR-degree build: histogram of dst + exclusive scan -> rowStart.
// ---------------------------------------------------------------------------
__global__ void hist_kernel(const int* __restrict__ dst, int* __restrict__ cnt, int E) {
    int t = blockIdx.x * blockDim.x + threadIdx.x;
    if (t < E) atomicAdd(&cnt[dst[t]], 1);
}

__global__ void block_sums_kernel(const int* __restrict__ cnt, int* __restrict__ bsum, int n) {
    __shared__ int red[256];
    int base = blockIdx.x * SCAN_CHUNK;
    int s = 0;
    for (int i = threadIdx.x; i < SCAN_CHUNK; i += 256) {
        int idx = base + i;
        s += (idx < n) ? cnt[idx] : 0;
    }
    red[threadIdx.x] = s;
    __syncthreads();
    for (int off = 128; off > 0; off >>= 1) {
        if (threadIdx.x < off) red[threadIdx.x] += red[threadIdx.x + off];
        __syncthreads();
    }
    if (threadIdx.x == 0) bsum[blockIdx.x] = red[0];
}

__global__ void scan_bsums_kernel(int* __restrict__ bsum, int nb) {
    __shared__ int s[256];
    int t = threadIdx.x;
    s[t] = (t < nb) ? bsum[t] : 0;
    __syncthreads();
    for (int off = 1; off < 256; off <<= 1) {
        int u = (t >= off) ? s[t - off] : 0;
        __syncthreads();
        s[t] += u;
        __syncthreads();
    }
    if (t < nb) bsum[t] = (t == 0) ? 0 : s[t - 1];   // exclusive
}

__global__ void scan_final_kernel(const int* __restrict__ cnt, const int* __restrict__ bsum,
                                  int* __restrict__ rowStart, int n, int E) {
    __shared__ int red[256];
    int t = threadIdx.x;
    int idx = blockIdx.x * SCAN_CHUNK + t * 4;
    int v0 = (idx + 0 < n) ? cnt[idx + 0] : 0;
    int v1 = (idx + 1 < n) ? cnt[idx + 1] : 0;
    int v2 = (idx + 2 < n) ? cnt[idx + 2] : 0;
    int v3 = (idx + 3 < n) ? cnt[idx + 3] : 0;
    red[t] = v0 + v1 + v2 + v3;
    __syncthreads();
    for (int off = 1; off < 256; off <<= 1) {
        int u = (t >= off) ? red[t - off] : 0;
        __syncthreads();
        red[t] += u;
        __syncthreads();
    }
    int excl = ((t == 0) ? 0 : red[t - 1]) + bsum[blockIdx.x];
    if (idx + 0 < n) rowStart[idx + 0] = excl;
    if (idx + 1 < n) rowStart[idx + 1] = excl + v0;
    if (idx + 2 < n) rowStart[idx + 2] = excl + v0 + v1;
    if (idx + 3 < n) rowStart[idx + 3] = excl + v0 + v1 + v2;
    if (blockIdx.x == 0 && t == 0) rowStart[n] = E;
}

__global__ __launch_bounds__(256)
void cursor_init_kernel(const int* __restrict__ rowStart, int* __restrict__ cursor,
                        int n, int nbuck) {
    int b = blockIdx.x * blockDim.x + threadIdx.x;
    if (b < nbuck) cursor[b] = rowStart[min(b << BSHIFT, n)];
}

// ---------------------------------------------------------------------------
// Bucket partition: (src, dst) -> packed 32-bit (src<<7 | dst&127), grouped
// by bucket (dst>>7) in `pairs`. LDS-staged; int LDS atomics only (native
// ds_add_u32 -- float LDS atomics are CAS loops on HIP, never use them).
// ---------------------------------------------------------------------------
__global__ __launch_bounds__(256)
void partition_kernel(const int* __restrict__ src, const int* __restrict__ dst,
                      int* __restrict__ cursor, unsigned* __restrict__ pairs,
                      int E, int nbuck) {
    __shared__ int lhist[MAXBUCK];        // counts, then local fill cursors
    __shared__ int lbase[MAXBUCK + 1];    // local exclusive scan
    __shared__ int gbase[MAXBUCK];        // reserved global positions
    __shared__ int red[256];
    __shared__ unsigned stage[PA_EDGES];  // 16 KB

    const int t = threadIdx.x;
    const int e0 = blockIdx.x * PA_EDGES;
    const int ecnt = min(PA_EDGES, E - e0);

    for (int i = t; i < MAXBUCK; i += 256) lhist[i] = 0;
    __syncthreads();
    for (int i = t; i < ecnt; i += 256) atomicAdd(&lhist[dst[e0 + i] >> BSHIFT], 1);
    __syncthreads();

    // exclusive scan over 1024 entries: each thread owns 4 consecutive slots
    const int c0 = lhist[4 * t], c1 = lhist[4 * t + 1];
    const int c2 = lhist[4 * t + 2], c3 = lhist[4 * t + 3];
    red[t] = c0 + c1 + c2 + c3;
    __syncthreads();
    for (int off = 1; off < 256; off <<= 1) {
        int u = (t >= off) ? red[t - off] : 0;
        __syncthreads();
        red[t] += u;
        __syncthreads();
    }
    const int excl = (t == 0) ? 0 : red[t - 1];
    lbase[4 * t]     = excl;
    lbase[4 * t + 1] = excl + c0;
    lbase[4 * t + 2] = excl + c0 + c1;
    lbase[4 * t + 3] = excl + c0 + c1 + c2;
    if (t == 255) lbase[MAXBUCK] = red[255];
    for (int b = t; b < nbuck; b += 256) {
        const int c = lhist[b];
        gbase[b] = c ? atomicAdd(&cursor[b], c) : 0;
    }
    __syncthreads();
    for (int i = t; i < MAXBUCK; i += 256) lhist[i] = 0;   // reuse as fill cursors
    __syncthreads();
    for (int i = t; i < ecnt; i += 256) {
        const int d = dst[e0 + i];
        const int b = d >> BSHIFT;
        const int p = lbase[b] + atomicAdd(&lhist[b], 1);
        stage[p] = ((unsigned)src[e0 + i] << BSHIFT) | (unsigned)(d & (BNODES - 1));
    }
    __syncthreads();
    for (int i = t; i < ecnt; i += 256) {
        int lo = 0, hi = MAXBUCK;
        while (hi - lo > 1) {
            const int mid = (lo + hi) >> 1;
            if (lbase[mid] <= i) lo = mid; else hi = mid;
        }
        pairs[gbase[lo] + (i - lbase[lo])] = stage[i];
    }
}

// ---------------------------------------------------------------------------
// Bucket CSR fill: one block per 128-node bucket; dst-sort the bucket's
// edges in LDS (int atomics), stream out coalesced -> csr sorted by dst.
// ---------------------------------------------------------------------------
__global__ __launch_bounds__(256)
void bucket_fill_kernel(const unsigned* __restrict__ pairs, const int* __restrict__ rowStart,
                        int* __restrict__ fill, int* __restrict__ csr, int n) {
    __shared__ int lcsr[PB_CAP];          // 16 KB
    __shared__ int lrow[BNODES + 1];
    __shared__ int lfill[BNODES];
    const int t = threadIdx.x;
    const int node0 = blockIdx.x << BSHIFT;
    const int bn = min(BNODES, n - node0);
    if (t <= BNODES) lrow[t] = rowStart[min(node0 + t, n)];
    if (t < BNODES) lfill[t] = 0;
    __syncthreads();
    const int base = lrow[0];
    const int cntE = lrow[bn] - base;
    if (cntE <= PB_CAP) {
        for (int i = t; i < cntE; i += 256) {
            const unsigned pr = pairs[base + i];
            const int dl = (int)(pr & (BNODES - 1));
            const int p = lrow[dl] - base + atomicAdd(&lfill[dl], 1);
            lcsr[p] = (int)(pr >> BSHIFT);
        }
        __syncthreads();
        for (int i = t; i < cntE; i += 256) csr[base + i] = lcsr[i];
    } else {   // safety fallback (statistically unreachable for random dst)
        for (int i = t; i < cntE; i += 256) {
            const unsigned pr = pairs[base + i];
            const int d = node0 + (int)(pr & (BNODES - 1));
            const int p = rowStart[d] + atomicAdd(&fill[d], 1);
            csr[p] = (int)(pr >> BSHIFT);
        }
    }
}

// ---------------------------------------------------------------------------
// Gather-mean: m[node] = mean(x[nbrs(node)]). One wave per node.
// Lane-group g (16 lanes) loads a row QUARTER via float4 -> each gather
// instruction puts 4 cache lines in flight (4 different neighbor rows).
// Tail handled by ONE fully-predicated 16-edge pass (no serial chain).
// ---------------------------------------------------------------------------
__device__ __forceinline__ void add4(float4& a, const float4 b) {
    a.x += b.x; a.y += b.y; a.z += b.z; a.w += b.w;
}

__global__ __launch_bounds__(256)
void aggmean_kernel(const float* __restrict__ xin, const int* __restrict__ rowStart,
                    const int* __restrict__ csr, float* __restrict__ m, int n) {
    const int lane = threadIdx.x & 63;
    const int g = lane >> 4;              // group 0..3
    const int gl = lane & 15;             // lane in group
    const int wave = threadIdx.x >> 6;
    const int gw = blockIdx.x * 4 + wave;
    const int nw = gridDim.x * 4;

    for (int node = gw; node < n; node += nw) {
        const int r0 = rowStart[node];
        const int r1 = rowStart[node + 1];
        float4 acc0 = make_float4(0.f, 0.f, 0.f, 0.f);
        float4 acc1 = make_float4(0.f, 0.f, 0.f, 0.f);

        int j = r0;
        for (; j + 16 <= r1; j += 16) {
            const int i0 = csr[j + 0  + g];
            const int i1 = csr[j + 4  + g];
            const int i2 = csr[j + 8  + g];
            const int i3 = csr[j + 12 + g];
            const float4 v0 = *(const float4*)&xin[(size_t)i0 * D + gl * 4];
            const float4 v1 = *(const float4*)&xin[(size_t)i1 * D + gl * 4];
            const float4 v2 = *(const float4*)&xin[(size_t)i2 * D + gl * 4];
            const float4 v3 = *(const float4*)&xin[(size_t)i3 * D + gl * 4];
            add4(acc0, v0); add4(acc1, v1); add4(acc0, v2); add4(acc1, v3);
        }
        const int rem = r1 - j;
        if (rem > 0) {
            // all predicated loads issue concurrently under exec masks
            if (0 + g < rem) {
                const int s = csr[j + 0 + g];
                add4(acc0, *(const float4*)&xin[(size_t)s * D + gl * 4]);
            }
            if (4 + g < rem) {
                const int s = csr[j + 4 + g];
                add4(acc1, *(const float4*)&xin[(size_t)s * D + gl * 4]);
            }
            if (8 + g < rem) {
                const int s = csr[j + 8 + g];
                add4(acc0, *(const float4*)&xin[(size_t)s * D + gl * 4]);
            }
            if (12 + g < rem) {
                const int s = csr[j + 12 + g];
                add4(acc1, *(const float4*)&xin[(size_t)s * D + gl * 4]);
            }
        }

        float4 a;
        a.x = acc0.x + acc1.x; a.y = acc0.y + acc1.y;
        a.z = acc0.z + acc1.z; a.w = acc0.w + acc1.w;
        // reduce across the 4 lane-groups (lanes l, l+16, l+32, l+48)
        a.x += __shfl_xor(a.x, 16); a.y += __shfl_xor(a.y, 16);
        a.z += __shfl_xor(a.z, 16); a.w += __shfl_xor(a.w, 16);
        a.x += __shfl_xor(a.x, 32); a.y += __shfl_xor(a.y, 32);
        a.z += __shfl_xor(a.z, 32); a.w += __shfl_xor(a.w, 32);

        if (lane < 16) {
            const float rdeg = 1.0f / fmaxf((float)(r1 - r0), 1.0f);
            float4 o = make_float4(a.x * rdeg, a.y * rdeg, a.z * rdeg, a.w * rdeg);
            *(float4*)&m[(size_t)node * D + gl * 4] = o;
        }
    }
}

// ---------------------------------------------------------------------------
// Fused SAGE transform: h = ELU(m@Wa + ba + x@Wb). Both weight columns
// register-resident; input rows broadcast via readlane.
// FINAL: out = h@Wlin + blin chained (third register column).
// ---------------------------------------------------------------------------
template <bool FINAL>
__global__ __launch_bounds__(256, 2)
void fused_mm_kernel(const float* __restrict__ m,
                     const float* __restrict__ xres,
                     const float* __restrict__ Wa,
                     const float* __restrict__ ba,
                     const float* __restrict__ Wb,
                     const float* __restrict__ Wlin,
                     const float* __restrict__ blin,
                     float* __restrict__ out,
                     int n) {
    const int lane = threadIdx.x & 63;
    const int wave = threadIdx.x >> 6;
    const int gw = blockIdx.x * 4 + wave;
    const int nw = gridDim.x * 4;

    float wa[D], wb[D], wl[FINAL ? D : 1];
#pragma unroll
    for (int k = 0; k < D; ++k) wa[k] = Wa[k * D + lane];   // column `lane`
#pragma unroll
    for (int k = 0; k < D; ++k) wb[k] = Wb[k * D + lane];
    if (FINAL) {
#pragma unroll
        for (int k = 0; k < D; ++k) wl[k] = Wlin[k * D + lane];
    }
    const float bva = ba[lane];
    const float bvl = FINAL ? blin[lane] : 0.0f;

    for (int node = gw; node < n; node += nw) {
        const unsigned mu = __float_as_uint(m[(size_t)node * D + lane]);
        const unsigned xu = __float_as_uint(xres[(size_t)node * D + lane]);
        float o0 = bva, o1 = 0.0f, o2 = 0.0f, o3 = 0.0f;
#pragma unroll
        for (int k = 0; k < D; k += 4) {
            const float sm0 = __uint_as_float(__builtin_amdgcn_readlane(mu, k + 0));
            const float sm1 = __uint_as_float(__builtin_amdgcn_readlane(mu, k + 1));
            const float sm2 = __uint_as_float(__builtin_amdgcn_readlane(mu, k + 2));
            const float sm3 = __uint_as_float(__builtin_amdgcn_readlane(mu, k + 3));
            const float sx0 = __uint_as_float(__builtin_amdgcn_readlane(xu, k + 0));
            const float sx1 = __uint_as_float(__builtin_amdgcn_readlane(xu, k + 1));
            const float sx2 = __uint_as_float(__builtin_amdgcn_readlane(xu, k + 2));
            const float sx3 = __uint_as_float(__builtin_amdgcn_readlane(xu, k + 3));
            o0 = fmaf(sm0, wa[k + 0], o0); o0 = fmaf(sx0, wb[k + 0], o0);
            o1 = fmaf(sm1, wa[k + 1], o1); o1 = fmaf(sx1, wb[k + 1], o1);
            o2 = fmaf(sm2, wa[k + 2], o2); o2 = fmaf(sx2, wb[k + 2], o2);
            o3 = fmaf(sm3, wa[k + 3], o3); o3 = fmaf(sx3, wb[k + 3], o3);
        }
        float h = (o0 + o1) + (o2 + o3);
        h = h > 0.0f ? h : expm1f(h);   // ELU(alpha=1)

        if (FINAL) {
            float o = bvl;
            const unsigned hu = __float_as_uint(h);
#pragma unroll
            for (int k = 0; k < D; ++k) {
                const float hk = __uint_as_float(__builtin_amdgcn_readlane(hu, k));
                o = fmaf(hk, wl[k], o);
            }
            out[(size_t)node * D + lane] = o;
        } else {
            out[(size_t)node * D + lane] = h;
        }
    }
}

extern "C" void kernel_launch(void* const* d_in, const int* in_sizes, int n_in,
                              void* d_out, int out_size, void* d_ws, size_t ws_size,
                              hipStream_t stream) {
    const float* x    = (const float*)d_in[0];
    const int*   ei   = (const int*)d_in[1];
    const float* W1l  = (const float*)d_in[2];
    const float* b1   = (const float*)d_in[3];
    const float* W1r  = (const float*)d_in[4];
    const float* W2l  = (const float*)d_in[5];
    const float* b2   = (const float*)d_in[6];
    const float* W2r  = (const float*)d_in[7];
    const float* Wlin = (const float*)d_in[8];
    const float* blin = (const float*)d_in[9];

    const int N_ = in_sizes[0] / D;      // 100000
    const int E_ = in_sizes[1] / 2;      // 1600000
    const int* src = ei;
    const int* dst = ei + E_;

    // workspace layout
    int* cnt      = (int*)d_ws;                     // N
    int* fill     = cnt + N_;                       // N (adjacent -> one memset)
    int* rowStart = fill + N_;                      // N+1
    int* bsum     = rowStart + N_ + 1;              // 256
    int* cursor   = bsum + 256;                     // MAXBUCK
    unsigned* pairs = (unsigned*)(cursor + MAXBUCK);// E (packed src<<7|dloc)
    int* csr      = (int*)(pairs + E_);             // E
    float* mbuf   = (float*)(csr + E_);             // N*64 (aggregated mean)
    float* hbuf   = mbuf + (size_t)N_ * D;          // N*64 (h1)

    const int nb    = (N_ + SCAN_CHUNK - 1) / SCAN_CHUNK;   // 98
    const int nbuck = (N_ + BNODES - 1) >> BSHIFT;          // 782

    hipMemsetAsync(cnt, 0, (size_t)2 * N_ * sizeof(int), stream);  // cnt + fill

    hist_kernel<<<(E_ + 255) / 256, 256, 0, stream>>>(dst, cnt, E_);
    block_sums_kernel<<<nb, 256, 0, stream>>>(cnt, bsum, N_);
    scan_bsums_kernel<<<1, 256, 0, stream>>>(bsum, nb);
    scan_final_kernel<<<nb, 256, 0, stream>>>(cnt, bsum, rowStart, N_, E_);
    cursor_init_kernel<<<(nbuck + 255) / 256, 256, 0, stream>>>(rowStart, cursor, N_, nbuck);
    partition_kernel<<<(E_ + PA_EDGES - 1) / PA_EDGES, 256, 0, stream>>>(
        src, dst, cursor, pairs, E_, nbuck);
    bucket_fill_kernel<<<nbuck, 256, 0, stream>>>(pairs, rowStart, fill, csr, N_);

    // Layer 1: m1 = mean(x[nbrs]) ; h1 = ELU(m1@W1l + b1 + x@W1r)
    aggmean_kernel<<<2048, 256, 0, stream>>>(x, rowStart, csr, mbuf, N_);
    fused_mm_kernel<false><<<2048, 256, 0, stream>>>(mbuf, x, W1l, b1, W1r,
                                                     nullptr, nullptr, hbuf, N_);
    // Layer 2: m2 = mean(h1[nbrs]) ; out = ELU(m2@W2l + b2 + h1@W2r) @ Wlin + blin
    aggmean_kernel<<<2048, 256, 0, stream>>>(hbuf, rowStart, csr, mbuf, N_);
    fused_mm_kernel<true><<<2048, 256, 0, stream>>>(mbuf, hbuf, W2l, b2, W2r,
                                                    Wlin, blin, (float*)d_out, N_);
}

// Round 4
// 391.274 us; speedup vs baseline: 4.0987x; 1.0236x over previous
//
#include <hip/hip_runtime.h>
#include <cmath>

#define D 64
#define SCAN_CHUNK 1024   // elements per scan block
#define PA_EDGES 4096     // edges per partition block
#define BSHIFT 7          // bucket = 128 nodes
#define BNODES 128
#define MAXBUCK 1024      // supports N <= 131072
#define PB_CAP 4096       // LDS csr staging per bucket (avg 2048, ~45 sigma)

// ---------------------------------------------------------------------------
// CSR-degree build: histogram of dst + exclusive scan -> rowStart.
// ---------------------------------------------------------------------------
__global__ void hist_kernel(const int* __restrict__ dst, int* __restrict__ cnt, int E) {
    int t = blockIdx.x * blockDim.x + threadIdx.x;
    if (t < E) atomicAdd(&cnt[dst[t]], 1);
}

__global__ void block_sums_kernel(const int* __restrict__ cnt, int* __restrict__ bsum, int n) {
    __shared__ int red[256];
    int base = blockIdx.x * SCAN_CHUNK;
    int s = 0;
    for (int i = threadIdx.x; i < SCAN_CHUNK; i += 256) {
        int idx = base + i;
        s += (idx < n) ? cnt[idx] : 0;
    }
    red[threadIdx.x] = s;
    __syncthreads();
    for (int off = 128; off > 0; off >>= 1) {
        if (threadIdx.x < off) red[threadIdx.x] += red[threadIdx.x + off];
        __syncthreads();
    }
    if (threadIdx.x == 0) bsum[blockIdx.x] = red[0];
}

__global__ void scan_bsums_kernel(int* __restrict__ bsum, int nb) {
    __shared__ int s[256];
    int t = threadIdx.x;
    s[t] = (t < nb) ? bsum[t] : 0;
    __syncthreads();
    for (int off = 1; off < 256; off <<= 1) {
        int u = (t >= off) ? s[t - off] : 0;
        __syncthreads();
        s[t] += u;
        __syncthreads();
    }
    if (t < nb) bsum[t] = (t == 0) ? 0 : s[t - 1];   // exclusive
}

__global__ void scan_final_kernel(const int* __restrict__ cnt, const int* __restrict__ bsum,
                                  int* __restrict__ rowStart, int n, int E) {
    __shared__ int red[256];
    int t = threadIdx.x;
    int idx = blockIdx.x * SCAN_CHUNK + t * 4;
    int v0 = (idx + 0 < n) ? cnt[idx + 0] : 0;
    int v1 = (idx + 1 < n) ? cnt[idx + 1] : 0;
    int v2 = (idx + 2 < n) ? cnt[idx + 2] : 0;
    int v3 = (idx + 3 < n) ? cnt[idx + 3] : 0;
    red[t] = v0 + v1 + v2 + v3;
    __syncthreads();
    for (int off = 1; off < 256; off <<= 1) {
        int u = (t >= off) ? red[t - off] : 0;
        __syncthreads();
        red[t] += u;
        __syncthreads();
    }
    int excl = ((t == 0) ? 0 : red[t - 1]) + bsum[blockIdx.x];
    if (idx + 0 < n) rowStart[idx + 0] = excl;
    if (idx + 1 < n) rowStart[idx + 1] = excl + v0;
    if (idx + 2 < n) rowStart[idx + 2] = excl + v0 + v1;
    if (idx + 3 < n) rowStart[idx + 3] = excl + v0 + v1 + v2;
    if (blockIdx.x == 0 && t == 0) rowStart[n] = E;
}

__global__ __launch_bounds__(256)
void cursor_init_kernel(const int* __restrict__ rowStart, int* __restrict__ cursor,
                        int n, int nbuck) {
    int b = blockIdx.x * blockDim.x + threadIdx.x;
    if (b < nbuck) cursor[b] = rowStart[min(b << BSHIFT, n)];
}

// ---------------------------------------------------------------------------
// Bucket partition: (src, dst) -> packed 32-bit (src<<7 | dst&127), grouped
// by bucket (dst>>7) in `pairs`. LDS-staged; int LDS atomics only (native
// ds_add_u32 -- float LDS atomics are CAS loops on HIP, never use them).
// ---------------------------------------------------------------------------
__global__ __launch_bounds__(256)
void partition_kernel(const int* __restrict__ src, const int* __restrict__ dst,
                      int* __restrict__ cursor, unsigned* __restrict__ pairs,
                      int E, int nbuck) {
    __shared__ int lhist[MAXBUCK];        // counts, then local fill cursors
    __shared__ int lbase[MAXBUCK + 1];    // local exclusive scan
    __shared__ int gbase[MAXBUCK];        // reserved global positions
    __shared__ int red[256];
    __shared__ unsigned stage[PA_EDGES];  // 16 KB

    const int t = threadIdx.x;
    const int e0 = blockIdx.x * PA_EDGES;
    const int ecnt = min(PA_EDGES, E - e0);

    for (int i = t; i < MAXBUCK; i += 256) lhist[i] = 0;
    __syncthreads();
    for (int i = t; i < ecnt; i += 256) atomicAdd(&lhist[dst[e0 + i] >> BSHIFT], 1);
    __syncthreads();

    // exclusive scan over 1024 entries: each thread owns 4 consecutive slots
    const int c0 = lhist[4 * t], c1 = lhist[4 * t + 1];
    const int c2 = lhist[4 * t + 2], c3 = lhist[4 * t + 3];
    red[t] = c0 + c1 + c2 + c3;
    __syncthreads();
    for (int off = 1; off < 256; off <<= 1) {
        int u = (t >= off) ? red[t - off] : 0;
        __syncthreads();
        red[t] += u;
        __syncthreads();
    }
    const int excl = (t == 0) ? 0 : red[t - 1];
    lbase[4 * t]     = excl;
    lbase[4 * t + 1] = excl + c0;
    lbase[4 * t + 2] = excl + c0 + c1;
    lbase[4 * t + 3] = excl + c0 + c1 + c2;
    if (t == 255) lbase[MAXBUCK] = red[255];
    for (int b = t; b < nbuck; b += 256) {
        const int c = lhist[b];
        gbase[b] = c ? atomicAdd(&cursor[b], c) : 0;
    }
    __syncthreads();
    for (int i = t; i < MAXBUCK; i += 256) lhist[i] = 0;   // reuse as fill cursors
    __syncthreads();
    for (int i = t; i < ecnt; i += 256) {
        const int d = dst[e0 + i];
        const int b = d >> BSHIFT;
        const int p = lbase[b] + atomicAdd(&lhist[b], 1);
        stage[p] = ((unsigned)src[e0 + i] << BSHIFT) | (unsigned)(d & (BNODES - 1));
    }
    __syncthreads();
    for (int i = t; i < ecnt; i += 256) {
        int lo = 0, hi = MAXBUCK;
        while (hi - lo > 1) {
            const int mid = (lo + hi) >> 1;
            if (lbase[mid] <= i) lo = mid; else hi = mid;
        }
        pairs[gbase[lo] + (i - lbase[lo])] = stage[i];
    }
}

// ---------------------------------------------------------------------------
// Bucket CSR fill: one block per 128-node bucket; dst-sort the bucket's
// edges in LDS (int atomics), stream out coalesced -> csr sorted by dst.
// ---------------------------------------------------------------------------
__global__ __launch_bounds__(256)
void bucket_fill_kernel(const unsigned* __restrict__ pairs, const int* __restrict__ rowStart,
                        int* __restrict__ fill, int* __restrict__ csr, int n) {
    __shared__ int lcsr[PB_CAP];          // 16 KB
    __shared__ int lrow[BNODES + 1];
    __shared__ int lfill[BNODES];
    const int t = threadIdx.x;
    const int node0 = blockIdx.x << BSHIFT;
    const int bn = min(BNODES, n - node0);
    if (t <= BNODES) lrow[t] = rowStart[min(node0 + t, n)];
    if (t < BNODES) lfill[t] = 0;
    __syncthreads();
    const int base = lrow[0];
    const int cntE = lrow[bn] - base;
    if (cntE <= PB_CAP) {
        for (int i = t; i < cntE; i += 256) {
            const unsigned pr = pairs[base + i];
            const int dl = (int)(pr & (BNODES - 1));
            const int p = lrow[dl] - base + atomicAdd(&lfill[dl], 1);
            lcsr[p] = (int)(pr >> BSHIFT);
        }
        __syncthreads();
        for (int i = t; i < cntE; i += 256) csr[base + i] = lcsr[i];
    } else {   // safety fallback (statistically unreachable for random dst)
        for (int i = t; i < cntE; i += 256) {
            const unsigned pr = pairs[base + i];
            const int d = node0 + (int)(pr & (BNODES - 1));
            const int p = rowStart[d] + atomicAdd(&fill[d], 1);
            csr[p] = (int)(pr >> BSHIFT);
        }
    }
}

// ---------------------------------------------------------------------------
// Gather-mean: m[node] = mean(x[nbrs(node)]). One wave per node.
// Lane-group g (16 lanes) loads a row QUARTER via float4 -> each gather
// instruction puts 4 cache lines in flight (4 different neighbor rows).
// Tail handled by ONE fully-predicated 16-edge pass (no serial chain).
// ---------------------------------------------------------------------------
__device__ __forceinline__ void add4(float4& a, const float4 b) {
    a.x += b.x; a.y += b.y; a.z += b.z; a.w += b.w;
}

__global__ __launch_bounds__(256)
void aggmean_kernel(const float* __restrict__ xin, const int* __restrict__ rowStart,
                    const int* __restrict__ csr, float* __restrict__ m, int n) {
    const int lane = threadIdx.x & 63;
    const int g = lane >> 4;              // group 0..3
    const int gl = lane & 15;             // lane in group
    const int wave = threadIdx.x >> 6;
    const int gw = blockIdx.x * 4 + wave;
    const int nw = gridDim.x * 4;

    for (int node = gw; node < n; node += nw) {
        const int r0 = rowStart[node];
        const int r1 = rowStart[node + 1];
        float4 acc0 = make_float4(0.f, 0.f, 0.f, 0.f);
        float4 acc1 = make_float4(0.f, 0.f, 0.f, 0.f);

        int j = r0;
        for (; j + 16 <= r1; j += 16) {
            const int i0 = csr[j + 0  + g];
            const int i1 = csr[j + 4  + g];
            const int i2 = csr[j + 8  + g];
            const int i3 = csr[j + 12 + g];
            const float4 v0 = *(const float4*)&xin[(size_t)i0 * D + gl * 4];
            const float4 v1 = *(const float4*)&xin[(size_t)i1 * D + gl * 4];
            const float4 v2 = *(const float4*)&xin[(size_t)i2 * D + gl * 4];
            const float4 v3 = *(const float4*)&xin[(size_t)i3 * D + gl * 4];
            add4(acc0, v0); add4(acc1, v1); add4(acc0, v2); add4(acc1, v3);
        }
        const int rem = r1 - j;
        if (rem > 0) {
            // all predicated loads issue concurrently under exec masks
            if (0 + g < rem) {
                const int s = csr[j + 0 + g];
                add4(acc0, *(const float4*)&xin[(size_t)s * D + gl * 4]);
            }
            if (4 + g < rem) {
                const int s = csr[j + 4 + g];
                add4(acc1, *(const float4*)&xin[(size_t)s * D + gl * 4]);
            }
            if (8 + g < rem) {
                const int s = csr[j + 8 + g];
                add4(acc0, *(const float4*)&xin[(size_t)s * D + gl * 4]);
            }
            if (12 + g < rem) {
                const int s = csr[j + 12 + g];
                add4(acc1, *(const float4*)&xin[(size_t)s * D + gl * 4]);
            }
        }

        float4 a;
        a.x = acc0.x + acc1.x; a.y = acc0.y + acc1.y;
        a.z = acc0.z + acc1.z; a.w = acc0.w + acc1.w;
        // reduce across the 4 lane-groups (lanes l, l+16, l+32, l+48)
        a.x += __shfl_xor(a.x, 16); a.y += __shfl_xor(a.y, 16);
        a.z += __shfl_xor(a.z, 16); a.w += __shfl_xor(a.w, 16);
        a.x += __shfl_xor(a.x, 32); a.y += __shfl_xor(a.y, 32);
        a.z += __shfl_xor(a.z, 32); a.w += __shfl_xor(a.w, 32);

        if (lane < 16) {
            const float rdeg = 1.0f / fmaxf((float)(r1 - r0), 1.0f);
            float4 o = make_float4(a.x * rdeg, a.y * rdeg, a.z * rdeg, a.w * rdeg);
            *(float4*)&m[(size_t)node * D + gl * 4] = o;
        }
    }
}

// ---------------------------------------------------------------------------
// Fused SAGE transform: h = ELU(m@Wa + ba + x@Wb). Both weight columns
// register-resident (128 VGPR). __launch_bounds__(256,3) -> VGPR cap 170:
// the proven round-1 budget that keeps weights resident. ((256,2) caused the
// compiler to demote the arrays: VGPR_Count=104 < 128, 89 us vs ~30.)
// Writing out == xres in place is safe: each node reads its row before
// writing it, no cross-node dependency.
// ---------------------------------------------------------------------------
__global__ __launch_bounds__(256, 3)
void fused_mm_kernel(const float* __restrict__ m,
                     const float* __restrict__ xres,
                     const float* __restrict__ Wa,
                     const float* __restrict__ ba,
                     const float* __restrict__ Wb,
                     float* __restrict__ out,
                     int n) {
    const int lane = threadIdx.x & 63;
    const int wave = threadIdx.x >> 6;
    const int gw = blockIdx.x * 4 + wave;
    const int nw = gridDim.x * 4;

    float wa[D], wb[D];
#pragma unroll
    for (int k = 0; k < D; ++k) wa[k] = Wa[k * D + lane];   // column `lane`
#pragma unroll
    for (int k = 0; k < D; ++k) wb[k] = Wb[k * D + lane];
    const float bva = ba[lane];

    for (int node = gw; node < n; node += nw) {
        const unsigned mu = __float_as_uint(m[(size_t)node * D + lane]);
        const unsigned xu = __float_as_uint(xres[(size_t)node * D + lane]);
        float o0 = bva, o1 = 0.0f, o2 = 0.0f, o3 = 0.0f;
#pragma unroll
        for (int k = 0; k < D; k += 4) {
            const float sm0 = __uint_as_float(__builtin_amdgcn_readlane(mu, k + 0));
            const float sm1 = __uint_as_float(__builtin_amdgcn_readlane(mu, k + 1));
            const float sm2 = __uint_as_float(__builtin_amdgcn_readlane(mu, k + 2));
            const float sm3 = __uint_as_float(__builtin_amdgcn_readlane(mu, k + 3));
            const float sx0 = __uint_as_float(__builtin_amdgcn_readlane(xu, k + 0));
            const float sx1 = __uint_as_float(__builtin_amdgcn_readlane(xu, k + 1));
            const float sx2 = __uint_as_float(__builtin_amdgcn_readlane(xu, k + 2));
            const float sx3 = __uint_as_float(__builtin_amdgcn_readlane(xu, k + 3));
            o0 = fmaf(sm0, wa[k + 0], o0); o0 = fmaf(sx0, wb[k + 0], o0);
            o1 = fmaf(sm1, wa[k + 1], o1); o1 = fmaf(sx1, wb[k + 1], o1);
            o2 = fmaf(sm2, wa[k + 2], o2); o2 = fmaf(sx2, wb[k + 2], o2);
            o3 = fmaf(sm3, wa[k + 3], o3); o3 = fmaf(sx3, wb[k + 3], o3);
        }
        float h = (o0 + o1) + (o2 + o3);
        h = h > 0.0f ? h : expm1f(h);   // ELU(alpha=1)
        out[(size_t)node * D + lane] = h;
    }
}

// ---------------------------------------------------------------------------
// Final linear: out = h@Wlin + blin. Single register-resident weight column
// (64 VGPR), __launch_bounds__(256,4) -- the round-0 ~20 us configuration.
// ---------------------------------------------------------------------------
__global__ __launch_bounds__(256, 4)
void final_mm_kernel(const float* __restrict__ h,
                     const float* __restrict__ W,
                     const float* __restrict__ bias,
                     float* __restrict__ out,
                     int n) {
    const int lane = threadIdx.x & 63;
    const int wave = threadIdx.x >> 6;
    const int gw = blockIdx.x * 4 + wave;
    const int nw = gridDim.x * 4;

    float w[D];
#pragma unroll
    for (int k = 0; k < D; ++k) w[k] = W[k * D + lane];   // column `lane`
    const float bv = bias[lane];

    for (int node = gw; node < n; node += nw) {
        const unsigned hu = __float_as_uint(h[(size_t)node * D + lane]);
        float o0 = bv, o1 = 0.0f, o2 = 0.0f, o3 = 0.0f;
#pragma unroll
        for (int k = 0; k < D; k += 4) {
            o0 = fmaf(__uint_as_float(__builtin_amdgcn_readlane(hu, k + 0)), w[k + 0], o0);
            o1 = fmaf(__uint_as_float(__builtin_amdgcn_readlane(hu, k + 1)), w[k + 1], o1);
            o2 = fmaf(__uint_as_float(__builtin_amdgcn_readlane(hu, k + 2)), w[k + 2], o2);
            o3 = fmaf(__uint_as_float(__builtin_amdgcn_readlane(hu, k + 3)), w[k + 3], o3);
        }
        out[(size_t)node * D + lane] = (o0 + o1) + (o2 + o3);
    }
}

extern "C" void kernel_launch(void* const* d_in, const int* in_sizes, int n_in,
                              void* d_out, int out_size, void* d_ws, size_t ws_size,
                              hipStream_t stream) {
    const float* x    = (const float*)d_in[0];
    const int*   ei   = (const int*)d_in[1];
    const float* W1l  = (const float*)d_in[2];
    const float* b1   = (const float*)d_in[3];
    const float* W1r  = (const float*)d_in[4];
    const float* W2l  = (const float*)d_in[5];
    const float* b2   = (const float*)d_in[6];
    const float* W2r  = (const float*)d_in[7];
    const float* Wlin = (const float*)d_in[8];
    const float* blin = (const float*)d_in[9];

    const int N_ = in_sizes[0] / D;      // 100000
    const int E_ = in_sizes[1] / 2;      // 1600000
    const int* src = ei;
    const int* dst = ei + E_;

    // workspace layout
    int* cnt      = (int*)d_ws;                     // N
    int* fill     = cnt + N_;                       // N (adjacent -> one memset)
    int* rowStart = fill + N_;                      // N+1
    int* bsum     = rowStart + N_ + 1;              // 256
    int* cursor   = bsum + 256;                     // MAXBUCK
    unsigned* pairs = (unsigned*)(cursor + MAXBUCK);// E (packed src<<7|dloc)
    int* csr      = (int*)(pairs + E_);             // E
    float* mbuf   = (float*)(csr + E_);             // N*64 (aggregated mean)
    float* hbuf   = mbuf + (size_t)N_ * D;          // N*64 (h1, then h2 in place)

    const int nb    = (N_ + SCAN_CHUNK - 1) / SCAN_CHUNK;   // 98
    const int nbuck = (N_ + BNODES - 1) >> BSHIFT;          // 782

    hipMemsetAsync(cnt, 0, (size_t)2 * N_ * sizeof(int), stream);  // cnt + fill

    hist_kernel<<<(E_ + 255) / 256, 256, 0, stream>>>(dst, cnt, E_);
    block_sums_kernel<<<nb, 256, 0, stream>>>(cnt, bsum, N_);
    scan_bsums_kernel<<<1, 256, 0, stream>>>(bsum, nb);
    scan_final_kernel<<<nb, 256, 0, stream>>>(cnt, bsum, rowStart, N_, E_);
    cursor_init_kernel<<<(nbuck + 255) / 256, 256, 0, stream>>>(rowStart, cursor, N_, nbuck);
    partition_kernel<<<(E_ + PA_EDGES - 1) / PA_EDGES, 256, 0, stream>>>(
        src, dst, cursor, pairs, E_, nbuck);
    bucket_fill_kernel<<<nbuck, 256, 0, stream>>>(pairs, rowStart, fill, csr, N_);

    // Layer 1: m1 = mean(x[nbrs]) ; h1 = ELU(m1@W1l + b1 + x@W1r)
    aggmean_kernel<<<2048, 256, 0, stream>>>(x, rowStart, csr, mbuf, N_);
    fused_mm_kernel<<<2048, 256, 0, stream>>>(mbuf, x, W1l, b1, W1r, hbuf, N_);
    // Layer 2: m2 = mean(h1[nbrs]) ; h2 = ELU(m2@W2l + b2 + h1@W2r)  (in place)
    aggmean_kernel<<<2048, 256, 0, stream>>>(hbuf, rowStart, csr, mbuf, N_);
    fused_mm_kernel<<<2048, 256, 0, stream>>>(mbuf, hbuf, W2l, b2, W2r, hbuf, N_);
    // Final: out = h2@Wlin + blin
    final_mm_kernel<<<2048, 256, 0, stream>>>(hbuf, Wlin, blin, (float*)d_out, N_);
}

// Round 5
// 357.177 us; speedup vs baseline: 4.4900x; 1.0955x over previous
//
#include <hip/hip_runtime.h>
#include <hip/hip_fp16.h>
#include <cmath>

#define D 64
#define SCAN_CHUNK 1024   // elements per scan block
#define PA_EDGES 4096     // edges per partition block
#define BSHIFT 7          // bucket = 128 nodes
#define BNODES 128
#define MAXBUCK 1024      // supports N <= 131072
#define PB_CAP 4096       // LDS csr staging per bucket (avg 2048, ~45 sigma)

// ---------------------------------------------------------------------------
// CSR-degree build: histogram of dst + exclusive scan -> rowStart.
// ---------------------------------------------------------------------------
__global__ void hist_kernel(const int* __restrict__ dst, int* __restrict__ cnt, int E) {
    int t = blockIdx.x * blockDim.x + threadIdx.x;
    if (t < E) atomicAdd(&cnt[dst[t]], 1);
}

__global__ void block_sums_kernel(const int* __restrict__ cnt, int* __restrict__ bsum, int n) {
    __shared__ int red[256];
    int base = blockIdx.x * SCAN_CHUNK;
    int s = 0;
    for (int i = threadIdx.x; i < SCAN_CHUNK; i += 256) {
        int idx = base + i;
        s += (idx < n) ? cnt[idx] : 0;
    }
    red[threadIdx.x] = s;
    __syncthreads();
    for (int off = 128; off > 0; off >>= 1) {
        if (threadIdx.x < off) red[threadIdx.x] += red[threadIdx.x + off];
        __syncthreads();
    }
    if (threadIdx.x == 0) bsum[blockIdx.x] = red[0];
}

__global__ void scan_bsums_kernel(int* __restrict__ bsum, int nb) {
    __shared__ int s[256];
    int t = threadIdx.x;
    s[t] = (t < nb) ? bsum[t] : 0;
    __syncthreads();
    for (int off = 1; off < 256; off <<= 1) {
        int u = (t >= off) ? s[t - off] : 0;
        __syncthreads();
        s[t] += u;
        __syncthreads();
    }
    if (t < nb) bsum[t] = (t == 0) ? 0 : s[t - 1];   // exclusive
}

__global__ void scan_final_kernel(const int* __restrict__ cnt, const int* __restrict__ bsum,
                                  int* __restrict__ rowStart, int n, int E) {
    __shared__ int red[256];
    int t = threadIdx.x;
    int idx = blockIdx.x * SCAN_CHUNK + t * 4;
    int v0 = (idx + 0 < n) ? cnt[idx + 0] : 0;
    int v1 = (idx + 1 < n) ? cnt[idx + 1] : 0;
    int v2 = (idx + 2 < n) ? cnt[idx + 2] : 0;
    int v3 = (idx + 3 < n) ? cnt[idx + 3] : 0;
    red[t] = v0 + v1 + v2 + v3;
    __syncthreads();
    for (int off = 1; off < 256; off <<= 1) {
        int u = (t >= off) ? red[t - off] : 0;
        __syncthreads();
        red[t] += u;
        __syncthreads();
    }
    int excl = ((t == 0) ? 0 : red[t - 1]) + bsum[blockIdx.x];
    if (idx + 0 < n) rowStart[idx + 0] = excl;
    if (idx + 1 < n) rowStart[idx + 1] = excl + v0;
    if (idx + 2 < n) rowStart[idx + 2] = excl + v0 + v1;
    if (idx + 3 < n) rowStart[idx + 3] = excl + v0 + v1 + v2;
    if (blockIdx.x == 0 && t == 0) rowStart[n] = E;
}

__global__ __launch_bounds__(256)
void cursor_init_kernel(const int* __restrict__ rowStart, int* __restrict__ cursor,
                        int n, int nbuck) {
    int b = blockIdx.x * blockDim.x + threadIdx.x;
    if (b < nbuck) cursor[b] = rowStart[min(b << BSHIFT, n)];
}

// ---------------------------------------------------------------------------
// Bucket partition: (src, dst) -> packed 32-bit (src<<7 | dst&127), grouped
// by bucket (dst>>7) in `pairs`. LDS-staged; int LDS atomics only (native
// ds_add_u32 -- float LDS atomics are CAS loops on HIP, never use them).
// Write-out uses a parallel bucket-id LDS array (1 ds_read) instead of the
// old 10-step dependent binary search over lbase.
// ---------------------------------------------------------------------------
__global__ __launch_bounds__(256)
void partition_kernel(const int* __restrict__ src, const int* __restrict__ dst,
                      int* __restrict__ cursor, unsigned* __restrict__ pairs,
                      int E, int nbuck) {
    __shared__ int lhist[MAXBUCK];            // counts, then local fill cursors
    __shared__ int lbase[MAXBUCK];            // local exclusive scan
    __shared__ int gbase[MAXBUCK];            // reserved global positions
    __shared__ int red[256];
    __shared__ unsigned stage[PA_EDGES];      // 16 KB
    __shared__ unsigned short sbuck[PA_EDGES];// 8 KB bucket id per staged slot

    const int t = threadIdx.x;
    const int e0 = blockIdx.x * PA_EDGES;
    const int ecnt = min(PA_EDGES, E - e0);

    for (int i = t; i < MAXBUCK; i += 256) lhist[i] = 0;
    __syncthreads();
    for (int i = t; i < ecnt; i += 256) atomicAdd(&lhist[dst[e0 + i] >> BSHIFT], 1);
    __syncthreads();

    // exclusive scan over 1024 entries: each thread owns 4 consecutive slots
    const int c0 = lhist[4 * t], c1 = lhist[4 * t + 1];
    const int c2 = lhist[4 * t + 2], c3 = lhist[4 * t + 3];
    red[t] = c0 + c1 + c2 + c3;
    __syncthreads();
    for (int off = 1; off < 256; off <<= 1) {
        int u = (t >= off) ? red[t - off] : 0;
        __syncthreads();
        red[t] += u;
        __syncthreads();
    }
    const int excl = (t == 0) ? 0 : red[t - 1];
    lbase[4 * t]     = excl;
    lbase[4 * t + 1] = excl + c0;
    lbase[4 * t + 2] = excl + c0 + c1;
    lbase[4 * t + 3] = excl + c0 + c1 + c2;
    for (int b = t; b < nbuck; b += 256) {
        const int c = lhist[b];
        gbase[b] = c ? atomicAdd(&cursor[b], c) : 0;
    }
    __syncthreads();
    for (int i = t; i < MAXBUCK; i += 256) lhist[i] = 0;   // reuse as fill cursors
    __syncthreads();
    for (int i = t; i < ecnt; i += 256) {
        const int d = dst[e0 + i];
        const int b = d >> BSHIFT;
        const int p = lbase[b] + atomicAdd(&lhist[b], 1);
        stage[p] = ((unsigned)src[e0 + i] << BSHIFT) | (unsigned)(d & (BNODES - 1));
        sbuck[p] = (unsigned short)b;
    }
    __syncthreads();
    for (int i = t; i < ecnt; i += 256) {
        const int b = sbuck[i];
        pairs[gbase[b] + (i - lbase[b])] = stage[i];
    }
}

// ---------------------------------------------------------------------------
// Bucket CSR fill: one block per 128-node bucket; dst-sort the bucket's
// edges in LDS (int atomics), stream out coalesced -> csr sorted by dst.
// ---------------------------------------------------------------------------
__global__ __launch_bounds__(256)
void bucket_fill_kernel(const unsigned* __restrict__ pairs, const int* __restrict__ rowStart,
                        int* __restrict__ fill, int* __restrict__ csr, int n) {
    __shared__ int lcsr[PB_CAP];          // 16 KB
    __shared__ int lrow[BNODES + 1];
    __shared__ int lfill[BNODES];
    const int t = threadIdx.x;
    const int node0 = blockIdx.x << BSHIFT;
    const int bn = min(BNODES, n - node0);
    if (t <= BNODES) lrow[t] = rowStart[min(node0 + t, n)];
    if (t < BNODES) lfill[t] = 0;
    __syncthreads();
    const int base = lrow[0];
    const int cntE = lrow[bn] - base;
    if (cntE <= PB_CAP) {
        for (int i = t; i < cntE; i += 256) {
            const unsigned pr = pairs[base + i];
            const int dl = (int)(pr & (BNODES - 1));
            const int p = lrow[dl] - base + atomicAdd(&lfill[dl], 1);
            lcsr[p] = (int)(pr >> BSHIFT);
        }
        __syncthreads();
        for (int i = t; i < cntE; i += 256) csr[base + i] = lcsr[i];
    } else {   // safety fallback (statistically unreachable for random dst)
        for (int i = t; i < cntE; i += 256) {
            const unsigned pr = pairs[base + i];
            const int d = node0 + (int)(pr & (BNODES - 1));
            const int p = rowStart[d] + atomicAdd(&fill[d], 1);
            csr[p] = (int)(pr >> BSHIFT);
        }
    }
}

// ---------------------------------------------------------------------------
// f32 -> f16 cast (vectorized, grid-stride).
// ---------------------------------------------------------------------------
__global__ __launch_bounds__(256)
void cast_half_kernel(const float* __restrict__ in, __half* __restrict__ out, int n2) {
    const float2* in2 = (const float2*)in;
    __half2* out2 = (__half2*)out;
    int i = blockIdx.x * 256 + threadIdx.x;
    const int st = gridDim.x * 256;
    for (; i < n2; i += st) {
        const float2 v = in2[i];
        out2[i] = __floats2half2_rn(v.x, v.y);
    }
}

// ---------------------------------------------------------------------------
// Gather-mean from an fp16 feature copy: m[node] = mean(xh[nbrs(node)]).
// One wave per node; lane-group g (16 lanes) loads one neighbor row
// (64 halves = 128 B) via 8 B dwordx2 -> 4 rows in flight per batch at HALF
// the fabric traffic of the f32 version (261 MB -> ~140 MB per pass).
// Accumulation stays f32.
// ---------------------------------------------------------------------------
__device__ __forceinline__ void addh4(float4& a, const __half* __restrict__ p) {
    union { unsigned long long u; __half2 h[2]; } r;
    r.u = *(const unsigned long long*)p;       // 8 B load
    const float2 f0 = __half22float2(r.h[0]);
    const float2 f1 = __half22float2(r.h[1]);
    a.x += f0.x; a.y += f0.y; a.z += f1.x; a.w += f1.y;
}

__global__ __launch_bounds__(256)
void aggmean_kernel(const __half* __restrict__ xh, const int* __restrict__ rowStart,
                    const int* __restrict__ csr, float* __restrict__ m, int n) {
    const int lane = threadIdx.x & 63;
    const int g = lane >> 4;              // group 0..3
    const int gl = lane & 15;             // lane in group
    const int wave = threadIdx.x >> 6;
    const int gw = blockIdx.x * 4 + wave;
    const int nw = gridDim.x * 4;

    for (int node = gw; node < n; node += nw) {
        const int r0 = rowStart[node];
        const int r1 = rowStart[node + 1];
        float4 acc0 = make_float4(0.f, 0.f, 0.f, 0.f);
        float4 acc1 = make_float4(0.f, 0.f, 0.f, 0.f);

        int j = r0;
        for (; j + 16 <= r1; j += 16) {
            const int i0 = csr[j + 0  + g];
            const int i1 = csr[j + 4  + g];
            const int i2 = csr[j + 8  + g];
            const int i3 = csr[j + 12 + g];
            addh4(acc0, &xh[(size_t)i0 * D + gl * 4]);
            addh4(acc1, &xh[(size_t)i1 * D + gl * 4]);
            addh4(acc0, &xh[(size_t)i2 * D + gl * 4]);
            addh4(acc1, &xh[(size_t)i3 * D + gl * 4]);
        }
        const int rem = r1 - j;
        if (rem > 0) {
            // all predicated loads issue concurrently under exec masks
            if (0 + g < rem) {
                const int s = csr[j + 0 + g];
                addh4(acc0, &xh[(size_t)s * D + gl * 4]);
            }
            if (4 + g < rem) {
                const int s = csr[j + 4 + g];
                addh4(acc1, &xh[(size_t)s * D + gl * 4]);
            }
            if (8 + g < rem) {
                const int s = csr[j + 8 + g];
                addh4(acc0, &xh[(size_t)s * D + gl * 4]);
            }
            if (12 + g < rem) {
                const int s = csr[j + 12 + g];
                addh4(acc1, &xh[(size_t)s * D + gl * 4]);
            }
        }

        float4 a;
        a.x = acc0.x + acc1.x; a.y = acc0.y + acc1.y;
        a.z = acc0.z + acc1.z; a.w = acc0.w + acc1.w;
        // reduce across the 4 lane-groups (lanes l, l+16, l+32, l+48)
        a.x += __shfl_xor(a.x, 16); a.y += __shfl_xor(a.y, 16);
        a.z += __shfl_xor(a.z, 16); a.w += __shfl_xor(a.w, 16);
        a.x += __shfl_xor(a.x, 32); a.y += __shfl_xor(a.y, 32);
        a.z += __shfl_xor(a.z, 32); a.w += __shfl_xor(a.w, 32);

        if (lane < 16) {
            const float rdeg = 1.0f / fmaxf((float)(r1 - r0), 1.0f);
            float4 o = make_float4(a.x * rdeg, a.y * rdeg, a.z * rdeg, a.w * rdeg);
            *(float4*)&m[(size_t)node * D + gl * 4] = o;
        }
    }
}

// ---------------------------------------------------------------------------
// Fused SAGE transform: h = ELU(m@Wa + ba + x@Wb). Both weight columns
// register-resident (128 VGPR), __launch_bounds__(256,3) (VGPR cap 170 --
// proven to keep the arrays resident; (256,2) caused demotion to 104 VGPR).
// Optionally also emits an fp16 copy of h for the next layer's gather.
// Writing out == xres in place is safe (each node reads before writing).
// ---------------------------------------------------------------------------
__global__ __launch_bounds__(256, 3)
void fused_mm_kernel(const float* __restrict__ m,
                     const float* __restrict__ xres,
                     const float* __restrict__ Wa,
                     const float* __restrict__ ba,
                     const float* __restrict__ Wb,
                     float* __restrict__ out,
                     __half* __restrict__ hout,   // nullable
                     int n) {
    const int lane = threadIdx.x & 63;
    const int wave = threadIdx.x >> 6;
    const int gw = blockIdx.x * 4 + wave;
    const int nw = gridDim.x * 4;

    float wa[D], wb[D];
#pragma unroll
    for (int k = 0; k < D; ++k) wa[k] = Wa[k * D + lane];   // column `lane`
#pragma unroll
    for (int k = 0; k < D; ++k) wb[k] = Wb[k * D + lane];
    const float bva = ba[lane];

    for (int node = gw; node < n; node += nw) {
        const unsigned mu = __float_as_uint(m[(size_t)node * D + lane]);
        const unsigned xu = __float_as_uint(xres[(size_t)node * D + lane]);
        float o0 = bva, o1 = 0.0f, o2 = 0.0f, o3 = 0.0f;
#pragma unroll
        for (int k = 0; k < D; k += 4) {
            const float sm0 = __uint_as_float(__builtin_amdgcn_readlane(mu, k + 0));
            const float sm1 = __uint_as_float(__builtin_amdgcn_readlane(mu, k + 1));
            const float sm2 = __uint_as_float(__builtin_amdgcn_readlane(mu, k + 2));
            const float sm3 = __uint_as_float(__builtin_amdgcn_readlane(mu, k + 3));
            const float sx0 = __uint_as_float(__builtin_amdgcn_readlane(xu, k + 0));
            const float sx1 = __uint_as_float(__builtin_amdgcn_readlane(xu, k + 1));
            const float sx2 = __uint_as_float(__builtin_amdgcn_readlane(xu, k + 2));
            const float sx3 = __uint_as_float(__builtin_amdgcn_readlane(xu, k + 3));
            o0 = fmaf(sm0, wa[k + 0], o0); o0 = fmaf(sx0, wb[k + 0], o0);
            o1 = fmaf(sm1, wa[k + 1], o1); o1 = fmaf(sx1, wb[k + 1], o1);
            o2 = fmaf(sm2, wa[k + 2], o2); o2 = fmaf(sx2, wb[k + 2], o2);
            o3 = fmaf(sm3, wa[k + 3], o3); o3 = fmaf(sx3, wb[k + 3], o3);
        }
        float h = (o0 + o1) + (o2 + o3);
        h = h > 0.0f ? h : expm1f(h);   // ELU(alpha=1)
        out[(size_t)node * D + lane] = h;
        if (hout) hout[(size_t)node * D + lane] = __float2half_rn(h);
    }
}

// ---------------------------------------------------------------------------
// Final linear: out = h@Wlin + blin. Single register-resident weight column
// (64 VGPR), __launch_bounds__(256,4).
// ---------------------------------------------------------------------------
__global__ __launch_bounds__(256, 4)
void final_mm_kernel(const float* __restrict__ h,
                     const float* __restrict__ W,
                     const float* __restrict__ bias,
                     float* __restrict__ out,
                     int n) {
    const int lane = threadIdx.x & 63;
    const int wave = threadIdx.x >> 6;
    const int gw = blockIdx.x * 4 + wave;
    const int nw = gridDim.x * 4;

    float w[D];
#pragma unroll
    for (int k = 0; k < D; ++k) w[k] = W[k * D + lane];   // column `lane`
    const float bv = bias[lane];

    for (int node = gw; node < n; node += nw) {
        const unsigned hu = __float_as_uint(h[(size_t)node * D + lane]);
        float o0 = bv, o1 = 0.0f, o2 = 0.0f, o3 = 0.0f;
#pragma unroll
        for (int k = 0; k < D; k += 4) {
            o0 = fmaf(__uint_as_float(__builtin_amdgcn_readlane(hu, k + 0)), w[k + 0], o0);
            o1 = fmaf(__uint_as_float(__builtin_amdgcn_readlane(hu, k + 1)), w[k + 1], o1);
            o2 = fmaf(__uint_as_float(__builtin_amdgcn_readlane(hu, k + 2)), w[k + 2], o2);
            o3 = fmaf(__uint_as_float(__builtin_amdgcn_readlane(hu, k + 3)), w[k + 3], o3);
        }
        out[(size_t)node * D + lane] = (o0 + o1) + (o2 + o3);
    }
}

extern "C" void kernel_launch(void* const* d_in, const int* in_sizes, int n_in,
                              void* d_out, int out_size, void* d_ws, size_t ws_size,
                              hipStream_t stream) {
    const float* x    = (const float*)d_in[0];
    const int*   ei   = (const int*)d_in[1];
    const float* W1l  = (const float*)d_in[2];
    const float* b1   = (const float*)d_in[3];
    const float* W1r  = (const float*)d_in[4];
    const float* W2l  = (const float*)d_in[5];
    const float* b2   = (const float*)d_in[6];
    const float* W2r  = (const float*)d_in[7];
    const float* Wlin = (const float*)d_in[8];
    const float* blin = (const float*)d_in[9];

    const int N_ = in_sizes[0] / D;      // 100000
    const int E_ = in_sizes[1] / 2;      // 1600000
    const int* src = ei;
    const int* dst = ei + E_;

    // workspace layout
    int* cnt      = (int*)d_ws;                     // N
    int* fill     = cnt + N_;                       // N (adjacent -> one memset)
    int* rowStart = fill + N_;                      // N+1
    int* bsum     = rowStart + N_ + 1;              // 256
    int* cursor   = bsum + 256;                     // MAXBUCK
    unsigned* pairs = (unsigned*)(cursor + MAXBUCK);// E (packed src<<7|dloc)
    int* csr      = (int*)(pairs + E_);             // E
    size_t iofs = (size_t)((csr + E_) - (int*)d_ws);
    iofs = (iofs + 3) & ~(size_t)3;                 // 16B-align float region
    float* mbuf   = (float*)d_ws + iofs;            // N*64 (aggregated mean)
    float* hbuf   = mbuf + (size_t)N_ * D;          // N*64 (h1, then h2 in place)
    // fp16 feature buffer: holds x-half for layer 1, then h1-half for layer 2
    // (x-half is dead once aggmean#1 finishes; fused_mm#1 overwrites it).
    __half* fh    = (__half*)(hbuf + (size_t)N_ * D); // N*64 halves (12.8 MB)

    const int nb    = (N_ + SCAN_CHUNK - 1) / SCAN_CHUNK;   // 98
    const int nbuck = (N_ + BNODES - 1) >> BSHIFT;          // 782

    hipMemsetAsync(cnt, 0, (size_t)2 * N_ * sizeof(int), stream);  // cnt + fill

    hist_kernel<<<(E_ + 255) / 256, 256, 0, stream>>>(dst, cnt, E_);
    block_sums_kernel<<<nb, 256, 0, stream>>>(cnt, bsum, N_);
    scan_bsums_kernel<<<1, 256, 0, stream>>>(bsum, nb);
    scan_final_kernel<<<nb, 256, 0, stream>>>(cnt, bsum, rowStart, N_, E_);
    cursor_init_kernel<<<(nbuck + 255) / 256, 256, 0, stream>>>(rowStart, cursor, N_, nbuck);
    partition_kernel<<<(E_ + PA_EDGES - 1) / PA_EDGES, 256, 0, stream>>>(
        src, dst, cursor, pairs, E_, nbuck);
    bucket_fill_kernel<<<nbuck, 256, 0, stream>>>(pairs, rowStart, fill, csr, N_);
    cast_half_kernel<<<1024, 256, 0, stream>>>(x, fh, N_ * D / 2);

    // Layer 1: m1 = mean(xh[nbrs]) ; h1 = ELU(m1@W1l + b1 + x@W1r)  (+h1 fp16)
    aggmean_kernel<<<2048, 256, 0, stream>>>(fh, rowStart, csr, mbuf, N_);
    fused_mm_kernel<<<2048, 256, 0, stream>>>(mbuf, x, W1l, b1, W1r, hbuf, fh, N_);
    // Layer 2: m2 = mean(h1h[nbrs]) ; h2 = ELU(m2@W2l + b2 + h1@W2r)  (in place)
    aggmean_kernel<<<2048, 256, 0, stream>>>(fh, rowStart, csr, mbuf, N_);
    fused_mm_kernel<<<2048, 256, 0, stream>>>(mbuf, hbuf, W2l, b2, W2r, hbuf, nullptr, N_);
    // Final: out = h2@Wlin + blin
    final_mm_kernel<<<2048, 256, 0, stream>>>(hbuf, Wlin, blin, (float*)d_out, N_);
}

// Round 6
// 297.520 us; speedup vs baseline: 5.3903x; 1.2005x over previous
//
#include <hip/hip_runtime.h>
#include <hip/hip_fp16.h>
#include <cmath>

#define D 64
#define PA_EDGES 4096     // edges per partition/bhist block
#define BSHIFT 7          // bucket = 128 nodes
#define BNODES 128
#define MAXBUCK 1024      // supports N <= 131072
#define PB_CAP 4096       // LDS csr staging per bucket (avg 2048, ~45 sigma)

// ---------------------------------------------------------------------------
// Per-BUCKET histogram, LDS-privatized. Replaces the per-node hist_kernel
// whose 1.6M random device atomics cost 50 MB of HBM write traffic (65 us).
// Each block pre-aggregates 4096 edges in LDS, flushes <=nbuck atomics.
// ---------------------------------------------------------------------------
__global__ __launch_bounds__(256)
void bhist_kernel(const int* __restrict__ dst, int* __restrict__ bcnt, int E, int nbuck) {
    __shared__ int lh[MAXBUCK];
    const int t = threadIdx.x;
    const int e0 = blockIdx.x * PA_EDGES;
    const int ecnt = min(PA_EDGES, E - e0);
    for (int i = t; i < MAXBUCK; i += 256) lh[i] = 0;
    __syncthreads();
    for (int i = t; i < ecnt; i += 256) atomicAdd(&lh[dst[e0 + i] >> BSHIFT], 1);
    __syncthreads();
    for (int b = t; b < nbuck; b += 256) {
        const int c = lh[b];
        if (c) atomicAdd(&bcnt[b], c);
    }
}

// ---------------------------------------------------------------------------
// Exclusive scan of bucket counts -> bbase (and cursor copy). One block.
// bbase[nbuck] = E. Replaces block_sums/scan_bsums/scan_final/cursor_init.
// ---------------------------------------------------------------------------
__global__ __launch_bounds__(256)
void bucket_scan_kernel(const int* __restrict__ bcnt, int* __restrict__ bbase,
                        int* __restrict__ cursor, int nbuck, int E) {
    __shared__ int red[256];
    const int t = threadIdx.x;
    const int c0 = (4 * t + 0 < nbuck) ? bcnt[4 * t + 0] : 0;
    const int c1 = (4 * t + 1 < nbuck) ? bcnt[4 * t + 1] : 0;
    const int c2 = (4 * t + 2 < nbuck) ? bcnt[4 * t + 2] : 0;
    const int c3 = (4 * t + 3 < nbuck) ? bcnt[4 * t + 3] : 0;
    red[t] = c0 + c1 + c2 + c3;
    __syncthreads();
    for (int off = 1; off < 256; off <<= 1) {
        int u = (t >= off) ? red[t - off] : 0;
        __syncthreads();
        red[t] += u;
        __syncthreads();
    }
    const int excl = (t == 0) ? 0 : red[t - 1];
    const int e0 = excl, e1 = excl + c0, e2 = excl + c0 + c1, e3 = excl + c0 + c1 + c2;
    if (4 * t + 0 <= nbuck) { bbase[4 * t + 0] = e0; }
    if (4 * t + 1 <= nbuck) { bbase[4 * t + 1] = e1; }
    if (4 * t + 2 <= nbuck) { bbase[4 * t + 2] = e2; }
    if (4 * t + 3 <= nbuck) { bbase[4 * t + 3] = e3; }
    if (4 * t + 0 < nbuck) cursor[4 * t + 0] = e0;
    if (4 * t + 1 < nbuck) cursor[4 * t + 1] = e1;
    if (4 * t + 2 < nbuck) cursor[4 * t + 2] = e2;
    if (4 * t + 3 < nbuck) cursor[4 * t + 3] = e3;
    if (t == 255) bbase[nbuck] = E;   // total (exclusive scan end)
}

// ---------------------------------------------------------------------------
// Bucket partition: (src, dst) -> packed 32-bit (src<<7 | dst&127), grouped
// by bucket (dst>>7) in `pairs`. LDS-staged; int LDS atomics only (native
// ds_add_u32 -- float LDS atomics are CAS loops on HIP, never use them).
// Write-out uses a parallel bucket-id LDS array (1 ds_read) instead of a
// dependent binary search.
// ---------------------------------------------------------------------------
__global__ __launch_bounds__(256)
void partition_kernel(const int* __restrict__ src, const int* __restrict__ dst,
                      int* __restrict__ cursor, unsigned* __restrict__ pairs,
                      int E, int nbuck) {
    __shared__ int lhist[MAXBUCK];            // counts, then local fill cursors
    __shared__ int lbase[MAXBUCK];            // local exclusive scan
    __shared__ int gbase[MAXBUCK];            // reserved global positions
    __shared__ int red[256];
    __shared__ unsigned stage[PA_EDGES];      // 16 KB
    __shared__ unsigned short sbuck[PA_EDGES];// 8 KB bucket id per staged slot

    const int t = threadIdx.x;
    const int e0 = blockIdx.x * PA_EDGES;
    const int ecnt = min(PA_EDGES, E - e0);

    for (int i = t; i < MAXBUCK; i += 256) lhist[i] = 0;
    __syncthreads();
    for (int i = t; i < ecnt; i += 256) atomicAdd(&lhist[dst[e0 + i] >> BSHIFT], 1);
    __syncthreads();

    // exclusive scan over 1024 entries: each thread owns 4 consecutive slots
    const int c0 = lhist[4 * t], c1 = lhist[4 * t + 1];
    const int c2 = lhist[4 * t + 2], c3 = lhist[4 * t + 3];
    red[t] = c0 + c1 + c2 + c3;
    __syncthreads();
    for (int off = 1; off < 256; off <<= 1) {
        int u = (t >= off) ? red[t - off] : 0;
        __syncthreads();
        red[t] += u;
        __syncthreads();
    }
    const int excl = (t == 0) ? 0 : red[t - 1];
    lbase[4 * t]     = excl;
    lbase[4 * t + 1] = excl + c0;
    lbase[4 * t + 2] = excl + c0 + c1;
    lbase[4 * t + 3] = excl + c0 + c1 + c2;
    for (int b = t; b < nbuck; b += 256) {
        const int c = lhist[b];
        gbase[b] = c ? atomicAdd(&cursor[b], c) : 0;
    }
    __syncthreads();
    for (int i = t; i < MAXBUCK; i += 256) lhist[i] = 0;   // reuse as fill cursors
    __syncthreads();
    for (int i = t; i < ecnt; i += 256) {
        const int d = dst[e0 + i];
        const int b = d >> BSHIFT;
        const int p = lbase[b] + atomicAdd(&lhist[b], 1);
        stage[p] = ((unsigned)src[e0 + i] << BSHIFT) | (unsigned)(d & (BNODES - 1));
        sbuck[p] = (unsigned short)b;
    }
    __syncthreads();
    for (int i = t; i < ecnt; i += 256) {
        const int b = sbuck[i];
        pairs[gbase[b] + (i - lbase[b])] = stage[i];
    }
}

// ---------------------------------------------------------------------------
// Bucket CSR fill + per-node rowStart derivation. One block per 128-node
// bucket. Counts per-node degrees in LDS (128 native int atomics), scans
// them on-chip, writes rowStart coalesced, dst-sorts the bucket's edges in
// LDS, streams csr out coalesced. No per-node global histogram anywhere.
// ---------------------------------------------------------------------------
__global__ __launch_bounds__(256)
void bucket_fill_kernel(const unsigned* __restrict__ pairs, const int* __restrict__ bbase,
                        int* __restrict__ rowStart, int* __restrict__ csr, int n, int E) {
    __shared__ int lcsr[PB_CAP];          // 16 KB
    __shared__ int lcnt[BNODES];          // per-node degree
    __shared__ int lrs[BNODES];           // per-node row start (bucket-relative)
    __shared__ int s[BNODES];             // scan workspace
    __shared__ int lfill[BNODES];
    const int t = threadIdx.x;
    const int node0 = blockIdx.x << BSHIFT;
    const int bn = min(BNODES, n - node0);
    const int base = bbase[blockIdx.x];
    const int cntE = bbase[blockIdx.x + 1] - base;

    if (t < BNODES) { lcnt[t] = 0; lfill[t] = 0; }
    __syncthreads();
    for (int i = t; i < cntE; i += 256)
        atomicAdd(&lcnt[pairs[base + i] & (BNODES - 1)], 1);
    __syncthreads();
    // inclusive scan of 128 counts (Hillis-Steele), then exclusive shift
    if (t < BNODES) s[t] = lcnt[t];
    __syncthreads();
    for (int off = 1; off < BNODES; off <<= 1) {
        int u = (t >= off && t < BNODES) ? s[t - off] : 0;
        __syncthreads();
        if (t < BNODES) s[t] += u;
        __syncthreads();
    }
    if (t < BNODES) lrs[t] = (t == 0) ? 0 : s[t - 1];
    __syncthreads();
    // publish global rowStart (coalesced, one write per node)
    if (t < bn) rowStart[node0 + t] = base + lrs[t];
    if (blockIdx.x == gridDim.x - 1 && t == 0) rowStart[n] = E;

    if (cntE <= PB_CAP) {
        for (int i = t; i < cntE; i += 256) {
            const unsigned pr = pairs[base + i];
            const int dl = (int)(pr & (BNODES - 1));
            const int p = lrs[dl] + atomicAdd(&lfill[dl], 1);
            lcsr[p] = (int)(pr >> BSHIFT);
        }
        __syncthreads();
        for (int i = t; i < cntE; i += 256) csr[base + i] = lcsr[i];
    } else {   // safety fallback (statistically unreachable for random dst)
        for (int i = t; i < cntE; i += 256) {
            const unsigned pr = pairs[base + i];
            const int dl = (int)(pr & (BNODES - 1));
            const int p = base + lrs[dl] + atomicAdd(&lfill[dl], 1);
            csr[p] = (int)(pr >> BSHIFT);
        }
    }
}

// ---------------------------------------------------------------------------
// f32 -> f16 cast (vectorized, grid-stride).
// ---------------------------------------------------------------------------
__global__ __launch_bounds__(256)
void cast_half_kernel(const float* __restrict__ in, __half* __restrict__ out, int n2) {
    const float2* in2 = (const float2*)in;
    __half2* out2 = (__half2*)out;
    int i = blockIdx.x * 256 + threadIdx.x;
    const int st = gridDim.x * 256;
    for (; i < n2; i += st) {
        const float2 v = in2[i];
        out2[i] = __floats2half2_rn(v.x, v.y);
    }
}

// ---------------------------------------------------------------------------
// Gather-mean from an fp16 feature copy: m[node] = mean(xh[nbrs(node)]).
// One wave per node; lane-group g (16 lanes) loads one neighbor row
// (64 halves = 128 B) via 8 B dwordx2 -> 4 rows in flight per batch at HALF
// the f32 fabric traffic. Accumulation stays f32.
// ---------------------------------------------------------------------------
__device__ __forceinline__ void addh4(float4& a, const __half* __restrict__ p) {
    union { unsigned long long u; __half2 h[2]; } r;
    r.u = *(const unsigned long long*)p;       // 8 B load
    const float2 f0 = __half22float2(r.h[0]);
    const float2 f1 = __half22float2(r.h[1]);
    a.x += f0.x; a.y += f0.y; a.z += f1.x; a.w += f1.y;
}

__global__ __launch_bounds__(256)
void aggmean_kernel(const __half* __restrict__ xh, const int* __restrict__ rowStart,
                    const int* __restrict__ csr, float* __restrict__ m, int n) {
    const int lane = threadIdx.x & 63;
    const int g = lane >> 4;              // group 0..3
    const int gl = lane & 15;             // lane in group
    const int wave = threadIdx.x >> 6;
    const int gw = blockIdx.x * 4 + wave;
    const int nw = gridDim.x * 4;

    for (int node = gw; node < n; node += nw) {
        const int r0 = rowStart[node];
        const int r1 = rowStart[node + 1];
        float4 acc0 = make_float4(0.f, 0.f, 0.f, 0.f);
        float4 acc1 = make_float4(0.f, 0.f, 0.f, 0.f);

        int j = r0;
        for (; j + 16 <= r1; j += 16) {
            const int i0 = csr[j + 0  + g];
            const int i1 = csr[j + 4  + g];
            const int i2 = csr[j + 8  + g];
            const int i3 = csr[j + 12 + g];
            addh4(acc0, &xh[(size_t)i0 * D + gl * 4]);
            addh4(acc1, &xh[(size_t)i1 * D + gl * 4]);
            addh4(acc0, &xh[(size_t)i2 * D + gl * 4]);
            addh4(acc1, &xh[(size_t)i3 * D + gl * 4]);
        }
        const int rem = r1 - j;
        if (rem > 0) {
            // all predicated loads issue concurrently under exec masks
            if (0 + g < rem) {
                const int sidx = csr[j + 0 + g];
                addh4(acc0, &xh[(size_t)sidx * D + gl * 4]);
            }
            if (4 + g < rem) {
                const int sidx = csr[j + 4 + g];
                addh4(acc1, &xh[(size_t)sidx * D + gl * 4]);
            }
            if (8 + g < rem) {
                const int sidx = csr[j + 8 + g];
                addh4(acc0, &xh[(size_t)sidx * D + gl * 4]);
            }
            if (12 + g < rem) {
                const int sidx = csr[j + 12 + g];
                addh4(acc1, &xh[(size_t)sidx * D + gl * 4]);
            }
        }

        float4 a;
        a.x = acc0.x + acc1.x; a.y = acc0.y + acc1.y;
        a.z = acc0.z + acc1.z; a.w = acc0.w + acc1.w;
        // reduce across the 4 lane-groups (lanes l, l+16, l+32, l+48)
        a.x += __shfl_xor(a.x, 16); a.y += __shfl_xor(a.y, 16);
        a.z += __shfl_xor(a.z, 16); a.w += __shfl_xor(a.w, 16);
        a.x += __shfl_xor(a.x, 32); a.y += __shfl_xor(a.y, 32);
        a.z += __shfl_xor(a.z, 32); a.w += __shfl_xor(a.w, 32);

        if (lane < 16) {
            const float rdeg = 1.0f / fmaxf((float)(r1 - r0), 1.0f);
            float4 o = make_float4(a.x * rdeg, a.y * rdeg, a.z * rdeg, a.w * rdeg);
            *(float4*)&m[(size_t)node * D + gl * 4] = o;
        }
    }
}

// ---------------------------------------------------------------------------
// Fused SAGE transform: h = ELU(m@Wa + ba + x@Wb). Both weight columns
// register-resident (128 VGPR), __launch_bounds__(256,3) (VGPR cap 170 --
// proven to keep the arrays resident; (256,2) caused demotion to 104 VGPR).
// Optionally also emits an fp16 copy of h for the next layer's gather.
// Writing out == xres in place is safe (each node reads before writing).
// ---------------------------------------------------------------------------
__global__ __launch_bounds__(256, 3)
void fused_mm_kernel(const float* __restrict__ m,
                     const float* __restrict__ xres,
                     const float* __restrict__ Wa,
                     const float* __restrict__ ba,
                     const float* __restrict__ Wb,
                     float* __restrict__ out,
                     __half* __restrict__ hout,   // nullable
                     int n) {
    const int lane = threadIdx.x & 63;
    const int wave = threadIdx.x >> 6;
    const int gw = blockIdx.x * 4 + wave;
    const int nw = gridDim.x * 4;

    float wa[D], wb[D];
#pragma unroll
    for (int k = 0; k < D; ++k) wa[k] = Wa[k * D + lane];   // column `lane`
#pragma unroll
    for (int k = 0; k < D; ++k) wb[k] = Wb[k * D + lane];
    const float bva = ba[lane];

    for (int node = gw; node < n; node += nw) {
        const unsigned mu = __float_as_uint(m[(size_t)node * D + lane]);
        const unsigned xu = __float_as_uint(xres[(size_t)node * D + lane]);
        float o0 = bva, o1 = 0.0f, o2 = 0.0f, o3 = 0.0f;
#pragma unroll
        for (int k = 0; k < D; k += 4) {
            const float sm0 = __uint_as_float(__builtin_amdgcn_readlane(mu, k + 0));
            const float sm1 = __uint_as_float(__builtin_amdgcn_readlane(mu, k + 1));
            const float sm2 = __uint_as_float(__builtin_amdgcn_readlane(mu, k + 2));
            const float sm3 = __uint_as_float(__builtin_amdgcn_readlane(mu, k + 3));
            const float sx0 = __uint_as_float(__builtin_amdgcn_readlane(xu, k + 0));
            const float sx1 = __uint_as_float(__builtin_amdgcn_readlane(xu, k + 1));
            const float sx2 = __uint_as_float(__builtin_amdgcn_readlane(xu, k + 2));
            const float sx3 = __uint_as_float(__builtin_amdgcn_readlane(xu, k + 3));
            o0 = fmaf(sm0, wa[k + 0], o0); o0 = fmaf(sx0, wb[k + 0], o0);
            o1 = fmaf(sm1, wa[k + 1], o1); o1 = fmaf(sx1, wb[k + 1], o1);
            o2 = fmaf(sm2, wa[k + 2], o2); o2 = fmaf(sx2, wb[k + 2], o2);
            o3 = fmaf(sm3, wa[k + 3], o3); o3 = fmaf(sx3, wb[k + 3], o3);
        }
        float h = (o0 + o1) + (o2 + o3);
        h = h > 0.0f ? h : expm1f(h);   // ELU(alpha=1)
        out[(size_t)node * D + lane] = h;
        if (hout) hout[(size_t)node * D + lane] = __float2half_rn(h);
    }
}

// ---------------------------------------------------------------------------
// Final linear: out = h@Wlin + blin. Single register-resident weight column
// (64 VGPR), __launch_bounds__(256,4).
// ---------------------------------------------------------------------------
__global__ __launch_bounds__(256, 4)
void final_mm_kernel(const float* __restrict__ h,
                     const float* __restrict__ W,
                     const float* __restrict__ bias,
                     float* __restrict__ out,
                     int n) {
    const int lane = threadIdx.x & 63;
    const int wave = threadIdx.x >> 6;
    const int gw = blockIdx.x * 4 + wave;
    const int nw = gridDim.x * 4;

    float w[D];
#pragma unroll
    for (int k = 0; k < D; ++k) w[k] = W[k * D + lane];   // column `lane`
    const float bv = bias[lane];

    for (int node = gw; node < n; node += nw) {
        const unsigned hu = __float_as_uint(h[(size_t)node * D + lane]);
        float o0 = bv, o1 = 0.0f, o2 = 0.0f, o3 = 0.0f;
#pragma unroll
        for (int k = 0; k < D; k += 4) {
            o0 = fmaf(__uint_as_float(__builtin_amdgcn_readlane(hu, k + 0)), w[k + 0], o0);
            o1 = fmaf(__uint_as_float(__builtin_amdgcn_readlane(hu, k + 1)), w[k + 1], o1);
            o2 = fmaf(__uint_as_float(__builtin_amdgcn_readlane(hu, k + 2)), w[k + 2], o2);
            o3 = fmaf(__uint_as_float(__builtin_amdgcn_readlane(hu, k + 3)), w[k + 3], o3);
        }
        out[(size_t)node * D + lane] = (o0 + o1) + (o2 + o3);
    }
}

extern "C" void kernel_launch(void* const* d_in, const int* in_sizes, int n_in,
                              void* d_out, int out_size, void* d_ws, size_t ws_size,
                              hipStream_t stream) {
    const float* x    = (const float*)d_in[0];
    const int*   ei   = (const int*)d_in[1];
    const float* W1l  = (const float*)d_in[2];
    const float* b1   = (const float*)d_in[3];
    const float* W1r  = (const float*)d_in[4];
    const float* W2l  = (const float*)d_in[5];
    const float* b2   = (const float*)d_in[6];
    const float* W2r  = (const float*)d_in[7];
    const float* Wlin = (const float*)d_in[8];
    const float* blin = (const float*)d_in[9];

    const int N_ = in_sizes[0] / D;      // 100000
    const int E_ = in_sizes[1] / 2;      // 1600000
    const int* src = ei;
    const int* dst = ei + E_;

    // workspace layout
    int* bcnt     = (int*)d_ws;                     // MAXBUCK
    int* bbase    = bcnt + MAXBUCK;                 // MAXBUCK+1
    int* cursor   = bbase + MAXBUCK + 1;            // MAXBUCK
    int* rowStart = cursor + MAXBUCK;               // N+1
    unsigned* pairs = (unsigned*)(rowStart + N_ + 1);// E (packed src<<7|dloc)
    int* csr      = (int*)(pairs + E_);             // E
    size_t iofs = (size_t)((csr + E_) - (int*)d_ws);
    iofs = (iofs + 3) & ~(size_t)3;                 // 16B-align float region
    float* mbuf   = (float*)d_ws + iofs;            // N*64 (aggregated mean)
    float* hbuf   = mbuf + (size_t)N_ * D;          // N*64 (h1, then h2 in place)
    // fp16 feature buffer: holds x-half for layer 1, then h1-half for layer 2
    // (x-half is dead once aggmean#1 finishes; fused_mm#1 overwrites it).
    __half* fh    = (__half*)(hbuf + (size_t)N_ * D); // N*64 halves (12.8 MB)

    const int nbuck = (N_ + BNODES - 1) >> BSHIFT;          // 782
    const int npart = (E_ + PA_EDGES - 1) / PA_EDGES;       // 391

    hipMemsetAsync(bcnt, 0, (size_t)MAXBUCK * sizeof(int), stream);

    bhist_kernel<<<npart, 256, 0, stream>>>(dst, bcnt, E_, nbuck);
    bucket_scan_kernel<<<1, 256, 0, stream>>>(bcnt, bbase, cursor, nbuck, E_);
    partition_kernel<<<npart, 256, 0, stream>>>(src, dst, cursor, pairs, E_, nbuck);
    bucket_fill_kernel<<<nbuck, 256, 0, stream>>>(pairs, bbase, rowStart, csr, N_, E_);
    cast_half_kernel<<<1024, 256, 0, stream>>>(x, fh, N_ * D / 2);

    // Layer 1: m1 = mean(xh[nbrs]) ; h1 = ELU(m1@W1l + b1 + x@W1r)  (+h1 fp16)
    aggmean_kernel<<<2048, 256, 0, stream>>>(fh, rowStart, csr, mbuf, N_);
    fused_mm_kernel<<<2048, 256, 0, stream>>>(mbuf, x, W1l, b1, W1r, hbuf, fh, N_);
    // Layer 2: m2 = mean(h1h[nbrs]) ; h2 = ELU(m2@W2l + b2 + h1@W2r)  (in place)
    aggmean_kernel<<<2048, 256, 0, stream>>>(fh, rowStart, csr, mbuf, N_);
    fused_mm_kernel<<<2048, 256, 0, stream>>>(mbuf, hbuf, W2l, b2, W2r, hbuf, nullptr, N_);
    // Final: out = h2@Wlin + blin
    final_mm_kernel<<<2048, 256, 0, stream>>>(hbuf, Wlin, blin, (float*)d_out, N_);
}

// Round 7
// 296.916 us; speedup vs baseline: 5.4013x; 1.0020x over previous
//
#include <hip/hip_runtime.h>
#include <hip/hip_fp16.h>
#include <cmath>

#define D 64
#define PA_EDGES 4096     // edges per partition/bhist block
#define BSHIFT 7          // bucket = 128 nodes
#define BNODES 128
#define MAXBUCK 1024      // supports N <= 131072
#define PB_CAP 4096       // LDS csr staging per bucket (avg 2048, ~45 sigma)

// ---------------------------------------------------------------------------
// Per-BUCKET histogram, LDS-privatized. Each block pre-aggregates 4096 edges
// in LDS, flushes <=nbuck aggregated atomics (replaces 1.6M random atomics).
// ---------------------------------------------------------------------------
__global__ __launch_bounds__(256)
void bhist_kernel(const int* __restrict__ dst, int* __restrict__ bcnt, int E, int nbuck) {
    __shared__ int lh[MAXBUCK];
    const int t = threadIdx.x;
    const int e0 = blockIdx.x * PA_EDGES;
    const int ecnt = min(PA_EDGES, E - e0);
    for (int i = t; i < MAXBUCK; i += 256) lh[i] = 0;
    __syncthreads();
    for (int i = t; i < ecnt; i += 256) atomicAdd(&lh[dst[e0 + i] >> BSHIFT], 1);
    __syncthreads();
    for (int b = t; b < nbuck; b += 256) {
        const int c = lh[b];
        if (c) atomicAdd(&bcnt[b], c);
    }
}

// ---------------------------------------------------------------------------
// Exclusive scan of bucket counts -> bbase (and cursor copy). One block.
// ---------------------------------------------------------------------------
__global__ __launch_bounds__(256)
void bucket_scan_kernel(const int* __restrict__ bcnt, int* __restrict__ bbase,
                        int* __restrict__ cursor, int nbuck, int E) {
    __shared__ int red[256];
    const int t = threadIdx.x;
    const int c0 = (4 * t + 0 < nbuck) ? bcnt[4 * t + 0] : 0;
    const int c1 = (4 * t + 1 < nbuck) ? bcnt[4 * t + 1] : 0;
    const int c2 = (4 * t + 2 < nbuck) ? bcnt[4 * t + 2] : 0;
    const int c3 = (4 * t + 3 < nbuck) ? bcnt[4 * t + 3] : 0;
    red[t] = c0 + c1 + c2 + c3;
    __syncthreads();
    for (int off = 1; off < 256; off <<= 1) {
        int u = (t >= off) ? red[t - off] : 0;
        __syncthreads();
        red[t] += u;
        __syncthreads();
    }
    const int excl = (t == 0) ? 0 : red[t - 1];
    const int e0 = excl, e1 = excl + c0, e2 = excl + c0 + c1, e3 = excl + c0 + c1 + c2;
    if (4 * t + 0 <= nbuck) { bbase[4 * t + 0] = e0; }
    if (4 * t + 1 <= nbuck) { bbase[4 * t + 1] = e1; }
    if (4 * t + 2 <= nbuck) { bbase[4 * t + 2] = e2; }
    if (4 * t + 3 <= nbuck) { bbase[4 * t + 3] = e3; }
    if (4 * t + 0 < nbuck) cursor[4 * t + 0] = e0;
    if (4 * t + 1 < nbuck) cursor[4 * t + 1] = e1;
    if (4 * t + 2 < nbuck) cursor[4 * t + 2] = e2;
    if (4 * t + 3 < nbuck) cursor[4 * t + 3] = e3;
    if (t == 255) bbase[nbuck] = E;   // total (exclusive scan end)
}

// ---------------------------------------------------------------------------
// Bucket partition: (src, dst) -> packed 32-bit (src<<7 | dst&127), grouped
// by bucket (dst>>7) in `pairs`. LDS-staged; int LDS atomics only (native
// ds_add_u32 -- float LDS atomics are CAS loops on HIP, never use them).
// ---------------------------------------------------------------------------
__global__ __launch_bounds__(256)
void partition_kernel(const int* __restrict__ src, const int* __restrict__ dst,
                      int* __restrict__ cursor, unsigned* __restrict__ pairs,
                      int E, int nbuck) {
    __shared__ int lhist[MAXBUCK];            // counts, then local fill cursors
    __shared__ int lbase[MAXBUCK];            // local exclusive scan
    __shared__ int gbase[MAXBUCK];            // reserved global positions
    __shared__ int red[256];
    __shared__ unsigned stage[PA_EDGES];      // 16 KB
    __shared__ unsigned short sbuck[PA_EDGES];// 8 KB bucket id per staged slot

    const int t = threadIdx.x;
    const int e0 = blockIdx.x * PA_EDGES;
    const int ecnt = min(PA_EDGES, E - e0);

    for (int i = t; i < MAXBUCK; i += 256) lhist[i] = 0;
    __syncthreads();
    for (int i = t; i < ecnt; i += 256) atomicAdd(&lhist[dst[e0 + i] >> BSHIFT], 1);
    __syncthreads();

    // exclusive scan over 1024 entries: each thread owns 4 consecutive slots
    const int c0 = lhist[4 * t], c1 = lhist[4 * t + 1];
    const int c2 = lhist[4 * t + 2], c3 = lhist[4 * t + 3];
    red[t] = c0 + c1 + c2 + c3;
    __syncthreads();
    for (int off = 1; off < 256; off <<= 1) {
        int u = (t >= off) ? red[t - off] : 0;
        __syncthreads();
        red[t] += u;
        __syncthreads();
    }
    const int excl = (t == 0) ? 0 : red[t - 1];
    lbase[4 * t]     = excl;
    lbase[4 * t + 1] = excl + c0;
    lbase[4 * t + 2] = excl + c0 + c1;
    lbase[4 * t + 3] = excl + c0 + c1 + c2;
    for (int b = t; b < nbuck; b += 256) {
        const int c = lhist[b];
        gbase[b] = c ? atomicAdd(&cursor[b], c) : 0;
    }
    __syncthreads();
    for (int i = t; i < MAXBUCK; i += 256) lhist[i] = 0;   // reuse as fill cursors
    __syncthreads();
    for (int i = t; i < ecnt; i += 256) {
        const int d = dst[e0 + i];
        const int b = d >> BSHIFT;
        const int p = lbase[b] + atomicAdd(&lhist[b], 1);
        stage[p] = ((unsigned)src[e0 + i] << BSHIFT) | (unsigned)(d & (BNODES - 1));
        sbuck[p] = (unsigned short)b;
    }
    __syncthreads();
    for (int i = t; i < ecnt; i += 256) {
        const int b = sbuck[i];
        pairs[gbase[b] + (i - lbase[b])] = stage[i];
    }
}

// ---------------------------------------------------------------------------
// Bucket CSR fill + per-node rowStart derivation, fully on-chip.
// ---------------------------------------------------------------------------
__global__ __launch_bounds__(256)
void bucket_fill_kernel(const unsigned* __restrict__ pairs, const int* __restrict__ bbase,
                        int* __restrict__ rowStart, int* __restrict__ csr, int n, int E) {
    __shared__ int lcsr[PB_CAP];          // 16 KB
    __shared__ int lcnt[BNODES];          // per-node degree
    __shared__ int lrs[BNODES];           // per-node row start (bucket-relative)
    __shared__ int s[BNODES];             // scan workspace
    __shared__ int lfill[BNODES];
    const int t = threadIdx.x;
    const int node0 = blockIdx.x << BSHIFT;
    const int bn = min(BNODES, n - node0);
    const int base = bbase[blockIdx.x];
    const int cntE = bbase[blockIdx.x + 1] - base;

    if (t < BNODES) { lcnt[t] = 0; lfill[t] = 0; }
    __syncthreads();
    for (int i = t; i < cntE; i += 256)
        atomicAdd(&lcnt[pairs[base + i] & (BNODES - 1)], 1);
    __syncthreads();
    if (t < BNODES) s[t] = lcnt[t];
    __syncthreads();
    for (int off = 1; off < BNODES; off <<= 1) {
        int u = (t >= off && t < BNODES) ? s[t - off] : 0;
        __syncthreads();
        if (t < BNODES) s[t] += u;
        __syncthreads();
    }
    if (t < BNODES) lrs[t] = (t == 0) ? 0 : s[t - 1];
    __syncthreads();
    if (t < bn) rowStart[node0 + t] = base + lrs[t];
    if (blockIdx.x == gridDim.x - 1 && t == 0) rowStart[n] = E;

    if (cntE <= PB_CAP) {
        for (int i = t; i < cntE; i += 256) {
            const unsigned pr = pairs[base + i];
            const int dl = (int)(pr & (BNODES - 1));
            const int p = lrs[dl] + atomicAdd(&lfill[dl], 1);
            lcsr[p] = (int)(pr >> BSHIFT);
        }
        __syncthreads();
        for (int i = t; i < cntE; i += 256) csr[base + i] = lcsr[i];
    } else {   // safety fallback (statistically unreachable for random dst)
        for (int i = t; i < cntE; i += 256) {
            const unsigned pr = pairs[base + i];
            const int dl = (int)(pr & (BNODES - 1));
            const int p = base + lrs[dl] + atomicAdd(&lfill[dl], 1);
            csr[p] = (int)(pr >> BSHIFT);
        }
    }
}

// ---------------------------------------------------------------------------
// f32 -> f16 cast (vectorized, grid-stride).
// ---------------------------------------------------------------------------
__global__ __launch_bounds__(256)
void cast_half_kernel(const float* __restrict__ in, __half* __restrict__ out, int n2) {
    const float2* in2 = (const float2*)in;
    __half2* out2 = (__half2*)out;
    int i = blockIdx.x * 256 + threadIdx.x;
    const int st = gridDim.x * 256;
    for (; i < n2; i += st) {
        const float2 v = in2[i];
        out2[i] = __floats2half2_rn(v.x, v.y);
    }
}

// ---------------------------------------------------------------------------
// Gather-mean from an fp16 feature copy: m[node] = mean(xh[nbrs(node)]).
// One wave per node; lane-group g (16 lanes) loads one neighbor row (128 B)
// via 8 B dwordx2 -> 4 rows in flight per gather batch. f32 accumulation.
// ---------------------------------------------------------------------------
__device__ __forceinline__ void addh4(float4& a, const __half* __restrict__ p) {
    union { unsigned long long u; __half2 h[2]; } r;
    r.u = *(const unsigned long long*)p;       // 8 B load
    const float2 f0 = __half22float2(r.h[0]);
    const float2 f1 = __half22float2(r.h[1]);
    a.x += f0.x; a.y += f0.y; a.z += f1.x; a.w += f1.y;
}

__global__ __launch_bounds__(256)
void aggmean_kernel(const __half* __restrict__ xh, const int* __restrict__ rowStart,
                    const int* __restrict__ csr, float* __restrict__ m, int n) {
    const int lane = threadIdx.x & 63;
    const int g = lane >> 4;              // group 0..3
    const int gl = lane & 15;             // lane in group
    const int wave = threadIdx.x >> 6;
    const int gw = blockIdx.x * 4 + wave;
    const int nw = gridDim.x * 4;

    for (int node = gw; node < n; node += nw) {
        const int r0 = rowStart[node];
        const int r1 = rowStart[node + 1];
        float4 acc0 = make_float4(0.f, 0.f, 0.f, 0.f);
        float4 acc1 = make_float4(0.f, 0.f, 0.f, 0.f);

        int j = r0;
        for (; j + 16 <= r1; j += 16) {
            const int i0 = csr[j + 0  + g];
            const int i1 = csr[j + 4  + g];
            const int i2 = csr[j + 8  + g];
            const int i3 = csr[j + 12 + g];
            addh4(acc0, &xh[(size_t)i0 * D + gl * 4]);
            addh4(acc1, &xh[(size_t)i1 * D + gl * 4]);
            addh4(acc0, &xh[(size_t)i2 * D + gl * 4]);
            addh4(acc1, &xh[(size_t)i3 * D + gl * 4]);
        }
        const int rem = r1 - j;
        if (rem > 0) {
            if (0 + g < rem) {
                const int sidx = csr[j + 0 + g];
                addh4(acc0, &xh[(size_t)sidx * D + gl * 4]);
            }
            if (4 + g < rem) {
                const int sidx = csr[j + 4 + g];
                addh4(acc1, &xh[(size_t)sidx * D + gl * 4]);
            }
            if (8 + g < rem) {
                const int sidx = csr[j + 8 + g];
                addh4(acc0, &xh[(size_t)sidx * D + gl * 4]);
            }
            if (12 + g < rem) {
                const int sidx = csr[j + 12 + g];
                addh4(acc1, &xh[(size_t)sidx * D + gl * 4]);
            }
        }

        float4 a;
        a.x = acc0.x + acc1.x; a.y = acc0.y + acc1.y;
        a.z = acc0.z + acc1.z; a.w = acc0.w + acc1.w;
        a.x += __shfl_xor(a.x, 16); a.y += __shfl_xor(a.y, 16);
        a.z += __shfl_xor(a.z, 16); a.w += __shfl_xor(a.w, 16);
        a.x += __shfl_xor(a.x, 32); a.y += __shfl_xor(a.y, 32);
        a.z += __shfl_xor(a.z, 32); a.w += __shfl_xor(a.w, 32);

        if (lane < 16) {
            const float rdeg = 1.0f / fmaxf((float)(r1 - r0), 1.0f);
            float4 o = make_float4(a.x * rdeg, a.y * rdeg, a.z * rdeg, a.w * rdeg);
            *(float4*)&m[(size_t)node * D + gl * 4] = o;
        }
    }
}

// ---------------------------------------------------------------------------
// Fused SAGE transform: h = ELU(m@Wa + ba + x@Wb). Both weight columns
// register-resident. KEY FIX: pass every loaded weight through an empty
// asm barrier -- the asm output is an opaque def the compiler cannot
// rematerialize, so it MUST keep the 128 values in VGPRs. (Without this,
// hipcc re-loads W[k*64+lane] at every use: VGPR_Count=72, 256 VMEM
// issues/node, 54 us. Expected now: ~145 VGPR, ~30 us.)
// ---------------------------------------------------------------------------
__global__ __launch_bounds__(256, 3)
void fused_mm_kernel(const float* __restrict__ m,
                     const float* __restrict__ xres,
                     const float* __restrict__ Wa,
                     const float* __restrict__ ba,
                     const float* __restrict__ Wb,
                     float* __restrict__ out,
                     __half* __restrict__ hout,   // nullable
                     int n) {
    const int lane = threadIdx.x & 63;
    const int wave = threadIdx.x >> 6;
    const int gw = blockIdx.x * 4 + wave;
    const int nw = gridDim.x * 4;

    float wa[D], wb[D];
#pragma unroll
    for (int k = 0; k < D; ++k) wa[k] = Wa[k * D + lane];   // column `lane`
#pragma unroll
    for (int k = 0; k < D; ++k) wb[k] = Wb[k * D + lane];
#pragma unroll
    for (int k = 0; k < D; ++k) {
        asm volatile("" : "+v"(wa[k]));   // anti-remat: pin to VGPR
        asm volatile("" : "+v"(wb[k]));
    }
    const float bva = ba[lane];

    for (int node = gw; node < n; node += nw) {
        const unsigned mu = __float_as_uint(m[(size_t)node * D + lane]);
        const unsigned xu = __float_as_uint(xres[(size_t)node * D + lane]);
        float o0 = bva, o1 = 0.0f, o2 = 0.0f, o3 = 0.0f;
#pragma unroll
        for (int k = 0; k < D; k += 4) {
            const float sm0 = __uint_as_float(__builtin_amdgcn_readlane(mu, k + 0));
            const float sm1 = __uint_as_float(__builtin_amdgcn_readlane(mu, k + 1));
            const float sm2 = __uint_as_float(__builtin_amdgcn_readlane(mu, k + 2));
            const float sm3 = __uint_as_float(__builtin_amdgcn_readlane(mu, k + 3));
            const float sx0 = __uint_as_float(__builtin_amdgcn_readlane(xu, k + 0));
            const float sx1 = __uint_as_float(__builtin_amdgcn_readlane(xu, k + 1));
            const float sx2 = __uint_as_float(__builtin_amdgcn_readlane(xu, k + 2));
            const float sx3 = __uint_as_float(__builtin_amdgcn_readlane(xu, k + 3));
            o0 = fmaf(sm0, wa[k + 0], o0); o0 = fmaf(sx0, wb[k + 0], o0);
            o1 = fmaf(sm1, wa[k + 1], o1); o1 = fmaf(sx1, wb[k + 1], o1);
            o2 = fmaf(sm2, wa[k + 2], o2); o2 = fmaf(sx2, wb[k + 2], o2);
            o3 = fmaf(sm3, wa[k + 3], o3); o3 = fmaf(sx3, wb[k + 3], o3);
        }
        float h = (o0 + o1) + (o2 + o3);
        h = h > 0.0f ? h : expm1f(h);   // ELU(alpha=1)
        out[(size_t)node * D + lane] = h;
        if (hout) hout[(size_t)node * D + lane] = __float2half_rn(h);
    }
}

// ---------------------------------------------------------------------------
// Final linear: out = h@Wlin + blin. Single register-resident weight column
// (64 VGPR, anti-remat pinned), __launch_bounds__(256,4).
// ---------------------------------------------------------------------------
__global__ __launch_bounds__(256, 4)
void final_mm_kernel(const float* __restrict__ h,
                     const float* __restrict__ W,
                     const float* __restrict__ bias,
                     float* __restrict__ out,
                     int n) {
    const int lane = threadIdx.x & 63;
    const int wave = threadIdx.x >> 6;
    const int gw = blockIdx.x * 4 + wave;
    const int nw = gridDim.x * 4;

    float w[D];
#pragma unroll
    for (int k = 0; k < D; ++k) w[k] = W[k * D + lane];   // column `lane`
#pragma unroll
    for (int k = 0; k < D; ++k) asm volatile("" : "+v"(w[k]));   // anti-remat
    const float bv = bias[lane];

    for (int node = gw; node < n; node += nw) {
        const unsigned hu = __float_as_uint(h[(size_t)node * D + lane]);
        float o0 = bv, o1 = 0.0f, o2 = 0.0f, o3 = 0.0f;
#pragma unroll
        for (int k = 0; k < D; k += 4) {
            o0 = fmaf(__uint_as_float(__builtin_amdgcn_readlane(hu, k + 0)), w[k + 0], o0);
            o1 = fmaf(__uint_as_float(__builtin_amdgcn_readlane(hu, k + 1)), w[k + 1], o1);
            o2 = fmaf(__uint_as_float(__builtin_amdgcn_readlane(hu, k + 2)), w[k + 2], o2);
            o3 = fmaf(__uint_as_float(__builtin_amdgcn_readlane(hu, k + 3)), w[k + 3], o3);
        }
        out[(size_t)node * D + lane] = (o0 + o1) + (o2 + o3);
    }
}

extern "C" void kernel_launch(void* const* d_in, const int* in_sizes, int n_in,
                              void* d_out, int out_size, void* d_ws, size_t ws_size,
                              hipStream_t stream) {
    const float* x    = (const float*)d_in[0];
    const int*   ei   = (const int*)d_in[1];
    const float* W1l  = (const float*)d_in[2];
    const float* b1   = (const float*)d_in[3];
    const float* W1r  = (const float*)d_in[4];
    const float* W2l  = (const float*)d_in[5];
    const float* b2   = (const float*)d_in[6];
    const float* W2r  = (const float*)d_in[7];
    const float* Wlin = (const float*)d_in[8];
    const float* blin = (const float*)d_in[9];

    const int N_ = in_sizes[0] / D;      // 100000
    const int E_ = in_sizes[1] / 2;      // 1600000
    const int* src = ei;
    const int* dst = ei + E_;

    // workspace layout
    int* bcnt     = (int*)d_ws;                     // MAXBUCK
    int* bbase    = bcnt + MAXBUCK;                 // MAXBUCK+1
    int* cursor   = bbase + MAXBUCK + 1;            // MAXBUCK
    int* rowStart = cursor + MAXBUCK;               // N+1
    unsigned* pairs = (unsigned*)(rowStart + N_ + 1);// E (packed src<<7|dloc)
    int* csr      = (int*)(pairs + E_);             // E
    size_t iofs = (size_t)((csr + E_) - (int*)d_ws);
    iofs = (iofs + 3) & ~(size_t)3;                 // 16B-align float region
    float* mbuf   = (float*)d_ws + iofs;            // N*64 (aggregated mean)
    float* hbuf   = mbuf + (size_t)N_ * D;          // N*64 (h1, then h2 in place)
    // fp16 feature buffer: x-half for layer 1, then h1-half for layer 2
    __half* fh    = (__half*)(hbuf + (size_t)N_ * D); // N*64 halves (12.8 MB)

    const int nbuck = (N_ + BNODES - 1) >> BSHIFT;          // 782
    const int npart = (E_ + PA_EDGES - 1) / PA_EDGES;       // 391

    hipMemsetAsync(bcnt, 0, (size_t)MAXBUCK * sizeof(int), stream);

    bhist_kernel<<<npart, 256, 0, stream>>>(dst, bcnt, E_, nbuck);
    bucket_scan_kernel<<<1, 256, 0, stream>>>(bcnt, bbase, cursor, nbuck, E_);
    partition_kernel<<<npart, 256, 0, stream>>>(src, dst, cursor, pairs, E_, nbuck);
    bucket_fill_kernel<<<nbuck, 256, 0, stream>>>(pairs, bbase, rowStart, csr, N_, E_);
    cast_half_kernel<<<1024, 256, 0, stream>>>(x, fh, N_ * D / 2);

    // Layer 1: m1 = mean(xh[nbrs]) ; h1 = ELU(m1@W1l + b1 + x@W1r)  (+h1 fp16)
    aggmean_kernel<<<2048, 256, 0, stream>>>(fh, rowStart, csr, mbuf, N_);
    fused_mm_kernel<<<2048, 256, 0, stream>>>(mbuf, x, W1l, b1, W1r, hbuf, fh, N_);
    // Layer 2: m2 = mean(h1h[nbrs]) ; h2 = ELU(m2@W2l + b2 + h1@W2r)  (in place)
    aggmean_kernel<<<2048, 256, 0, stream>>>(fh, rowStart, csr, mbuf, N_);
    fused_mm_kernel<<<2048, 256, 0, stream>>>(mbuf, hbuf, W2l, b2, W2r, hbuf, nullptr, N_);
    // Final: out = h2@Wlin + blin
    final_mm_kernel<<<2048, 256, 0, stream>>>(hbuf, Wlin, blin, (float*)d_out, N_);
}